// Round 7
// baseline (319.823 us; speedup 1.0000x reference)
//
#include <hip/hip_runtime.h>
#include <cstdint>
#include <cstddef>

#define N_NODES 200000
#define N_FACES 400000
#define N_EDGES (3*N_FACES)
#define NBUCKETS 196           // ceil(200000/1024), 1024 node-ids per bucket
#define CAP_BUCKET 8192        // mean 6144, sigma~101 -> +20 sigma margin
#define FACES_PER_BLK 2048
#define MM_BLOCKS 500          // 12500 row-tiles of 16 rows, 25 per block
#define MM_ITERS 25
#define NB_AGG 2048            // agg2 blocks

typedef __attribute__((ext_vector_type(8))) short short8;
typedef __attribute__((ext_vector_type(4))) float f32x4;

__device__ __forceinline__ unsigned short f2bf(float f){
  unsigned u = __float_as_uint(f);
  u = u + 0x7fffu + ((u>>16)&1u);   // RNE
  return (unsigned short)(u>>16);
}

// ---- fp8 e4m3fn helpers ----------------------------------------------------
__device__ __forceinline__ unsigned f2fp8(float f){   // RNE encode
  unsigned sgn = (__float_as_uint(f) >> 24) & 0x80u;
  float a = fabsf(f);
  a = fminf(a, 448.f);
  unsigned out;
  if (a < 0.015625f){
    out = (unsigned)__float2int_rn(a * 512.f);        // subnormal, 0..8
  } else {
    unsigned m = __float_as_uint(a);
    m = m + 0xFFFFFu + ((m >> 20) & 1u);              // RNE at 3 mantissa bits
    int e = (int)(m >> 23) - 127;                     // -6..8
    out = ((unsigned)(e + 7) << 3) | ((m >> 20) & 7u);
  }
  return out | sgn;
}
__device__ __forceinline__ float fp8tof(unsigned b){  // exact decode (incl subnormals)
  unsigned t = ((b & 0x80u) << 24) | ((b & 0x7fu) << 20);
  return __uint_as_float(t) * 0x1p120f;
}
#if __has_builtin(__builtin_amdgcn_cvt_f32_fp8)
#define DEC_FP8(u, i) __builtin_amdgcn_cvt_f32_fp8((int)(u), (i))
#else
#define DEC_FP8(u, i) fp8tof(((u) >> ((i)*8)) & 0xffu)
#endif

// ---- CSR build, pass A: bin (src,dst) pairs by dst>>10 ---------------------
__global__ __launch_bounds__(256) void k_passA(const int* __restrict__ face,
                                               int* __restrict__ bfill,
                                               int2* __restrict__ pairs){
  __shared__ int hist[NBUCKETS], basel[NBUCKETS], rank[NBUCKETS];
  int tid = threadIdx.x;
  if (tid < NBUCKETS) hist[tid] = 0;
  __syncthreads();
  int f0 = blockIdx.x * FACES_PER_BLK + tid;
  int v0[8], v1[8], v2[8];
  #pragma unroll
  for (int k=0;k<8;++k){
    int f = f0 + k*256;
    if (f < N_FACES){
      v0[k] = face[f]; v1[k] = face[f + N_FACES]; v2[k] = face[f + 2*N_FACES];
    } else { v0[k] = 0; v1[k] = 0; v2[k] = 0; }
  }
  #pragma unroll
  for (int k=0;k<8;++k){
    if (v0[k] != v1[k]) atomicAdd(&hist[v1[k]>>10], 1);
    if (v1[k] != v2[k]) atomicAdd(&hist[v2[k]>>10], 1);
    if (v0[k] != v2[k]) atomicAdd(&hist[v2[k]>>10], 1);
  }
  __syncthreads();
  if (tid < NBUCKETS){
    basel[tid] = atomicAdd(&bfill[tid], hist[tid]);
    rank[tid] = 0;
  }
  __syncthreads();
  #pragma unroll
  for (int k=0;k<8;++k){
    if (v0[k] != v1[k]){
      int b = v1[k]>>10;
      int p = basel[b] + atomicAdd(&rank[b],1);
      if (p < CAP_BUCKET) pairs[(size_t)b*CAP_BUCKET + p] = make_int2(v0[k], v1[k]);
    }
    if (v1[k] != v2[k]){
      int b = v2[k]>>10;
      int p = basel[b] + atomicAdd(&rank[b],1);
      if (p < CAP_BUCKET) pairs[(size_t)b*CAP_BUCKET + p] = make_int2(v1[k], v2[k]);
    }
    if (v0[k] != v2[k]){
      int b = v2[k]>>10;
      int p = basel[b] + atomicAdd(&rank[b],1);
      if (p < CAP_BUCKET) pairs[(size_t)b*CAP_BUCKET + p] = make_int2(v0[k], v2[k]);
    }
  }
}

// ---- exclusive scan of the 196 bucket fills (one wave) ---------------------
__global__ void k_bscan(const int* __restrict__ bfill, int* __restrict__ bbase){
  int l = threadIdx.x;  // 64
  int v[4]; int s = 0;
  #pragma unroll
  for (int k=0;k<4;++k){ int i = l*4+k; v[k] = (i < NBUCKETS)? min(bfill[i], CAP_BUCKET) : 0; s += v[k]; }
  int inc = s;
  #pragma unroll
  for (int d=1; d<64; d<<=1){ int t = __shfl_up(inc, d); if (l >= d) inc += t; }
  int pre = inc - s;
  #pragma unroll
  for (int k=0;k<4;++k){ int i = l*4+k; if (i < NBUCKETS) bbase[i] = pre; pre += v[k]; }
}

// ---- CSR build, pass B: per-bucket LDS counting sort -----------------------
__global__ __launch_bounds__(512) void k_passB(const int2* __restrict__ pairs,
                                               const int* __restrict__ bfill,
                                               const int* __restrict__ bbase,
                                               int* __restrict__ offs, int* __restrict__ cnt,
                                               int* __restrict__ csr){
  __shared__ int lcnt[1024], lfill[1024], sc[512];
  __shared__ int lcsr[CAP_BUCKET];
  int b = blockIdx.x, tid = threadIdx.x;
  int nb = min(bfill[b], CAP_BUCKET);
  int base = bbase[b];
  const int2* bp = pairs + (size_t)b*CAP_BUCKET;
  lcnt[tid] = 0; lcnt[tid+512] = 0;
  __syncthreads();
  for (int i = tid; i < nb; i += 512){
    int2 e = bp[i];
    atomicAdd(&lcnt[e.y & 1023], 1);
  }
  __syncthreads();
  int c0 = lcnt[2*tid], c1 = lcnt[2*tid+1];
  int s = c0 + c1;
  sc[tid] = s; __syncthreads();
  for (int d=1; d<512; d<<=1){
    int v = (tid>=d)? sc[tid-d] : 0; __syncthreads();
    sc[tid] += v; __syncthreads();
  }
  int excl = sc[tid] - s;
  lfill[2*tid] = excl; lfill[2*tid+1] = excl + c0;
  int g0 = b*1024 + 2*tid, g1 = g0 + 1;
  if (g0 < N_NODES){ offs[g0] = base + excl;      cnt[g0] = c0; }
  if (g1 < N_NODES){ offs[g1] = base + excl + c0; cnt[g1] = c1; }
  __syncthreads();
  for (int i = tid; i < nb; i += 512){
    int2 e = bp[i];
    int p = atomicAdd(&lfill[e.y & 1023], 1);
    lcsr[p] = e.x;
  }
  __syncthreads();
  for (int i = tid; i < nb; i += 512){
    csr[base + i] = lcsr[i];
  }
}

// ---- stage-2 B pre-pack: [W2l|W2r] (256K x 256N) into MFMA fragment order --
// bp[((s*16+n)*64+l)*8+j] = Bstack[32s+8*(l>>4)+j][16n+(l&15)]
__global__ void k_bprep(const float* __restrict__ W2l, const float* __restrict__ W2r,
                        unsigned short* __restrict__ bp){
  int idx = blockIdx.x*256 + threadIdx.x;   // 65536 total
  int j = idx & 7, l = (idx>>3)&63, n = (idx>>9)&15, s = idx>>13;
  int k = 32*s + 8*(l>>4) + j;
  int c = 16*n + (l&15);
  float v = (c < 128)? W2l[k*128 + c] : W2r[k*128 + (c-128)];
  bp[idx] = f2bf(v);
}

// ---- stage-1 B pre-pack: [W1l;W1r] (6 x 256) K-padded to 32, frag order ----
__global__ void k_w1prep(const float* __restrict__ W1l, const float* __restrict__ W1r,
                         unsigned short* __restrict__ w1p){
  int idx = blockIdx.x*256 + threadIdx.x;   // 8192 total
  int j = idx & 7, l = (idx>>3)&63, n = idx>>9;   // n in [0,16)
  int k = 8*(l>>4) + j;
  int c = 16*n + (l&15);
  float v = 0.f;
  if (k < 3) v = W1l[k*256 + c];
  else if (k < 6) v = W1r[(k-3)*256 + c];
  w1p[idx] = f2bf(v);
}

// ---- x1: per node, mean of neighbor pos + own pos, packed bf16 [8] --------
__global__ void k_x1(const float* __restrict__ pos, const int* __restrict__ csr,
                     const int* __restrict__ offs, const int* __restrict__ cnt,
                     unsigned short* __restrict__ x1bf){
  int i = blockIdx.x*256 + threadIdx.x;
  if (i >= N_NODES) return;
  int off = offs[i], deg = cnt[i];
  float s0=0.f, s1=0.f, s2=0.f;
  int e = 0;
  for (; e+2 <= deg; e += 2){
    int a = csr[off+e], b = csr[off+e+1];
    const float* pa = pos + 3*a; const float* pb = pos + 3*b;
    s0 += pa[0] + pb[0]; s1 += pa[1] + pb[1]; s2 += pa[2] + pb[2];
  }
  if (e < deg){
    const float* pa = pos + 3*csr[off+e];
    s0 += pa[0]; s1 += pa[1]; s2 += pa[2];
  }
  float inv = 1.0f / (float)max(deg,1);
  float p0 = pos[3*i], p1 = pos[3*i+1], p2 = pos[3*i+2];
  uint4 pk;
  pk.x = (unsigned)f2bf(s0*inv) | ((unsigned)f2bf(s1*inv)<<16);
  pk.y = (unsigned)f2bf(s2*inv) | ((unsigned)f2bf(p0)<<16);
  pk.z = (unsigned)f2bf(p1)     | ((unsigned)f2bf(p2)<<16);
  pk.w = 0;
  *(uint4*)(x1bf + (size_t)i*8) = pk;
}

// ---- fused double GEMM: h1 = relu(X1@W1+b1) (MFMA, K=32 zero-padded),
//      yz = h1 @ [W2l|W2r] (MFMA), y/z stored compact fp8 -------------------
__global__ __launch_bounds__(256,2) void k_mm(
    const unsigned short* __restrict__ x1bf,
    const unsigned short* __restrict__ w1p,
    const float* __restrict__ b1,
    const unsigned short* __restrict__ bp,
    unsigned char* __restrict__ ybuf,
    unsigned char* __restrict__ zbuf){
  __shared__ unsigned short sh1[16*264];    // 16 rows x 528B stride
  __shared__ unsigned char epi[16*256];     // xor-swizzled fp8 staging
  int tid = threadIdx.x;
  int w = tid>>6, lane = tid&63, r = lane&15, g = lane>>4;

  // stage-2 B frags (cols 64w..64w+64), held whole kernel
  short8 B2[8][4];
  #pragma unroll
  for (int s=0;s<8;++s)
    #pragma unroll
    for (int n4=0;n4<4;++n4)
      B2[s][n4] = *(const short8*)(bp + ((size_t)((s*16 + 4*w + n4)*64 + lane))*8);
  // stage-1 B frags + bias
  short8 W1B[4];
  float b1r[4];
  #pragma unroll
  for (int n4=0;n4<4;++n4){
    W1B[n4] = *(const short8*)(w1p + ((size_t)((4*w + n4)*64 + lane))*8);
    b1r[n4] = b1[16*(4*w + n4) + r];
  }

  int tile = blockIdx.x;
  short8 a1 = {0,0,0,0,0,0,0,0};
  if (g == 0) a1 = *(const short8*)(x1bf + (size_t)(tile*16 + r)*8);

  for (int k=0;k<MM_ITERS;++k){
    int nt = tile + MM_BLOCKS;
    short8 a1n = {0,0,0,0,0,0,0,0};
    if (k+1 < MM_ITERS && g == 0)
      a1n = *(const short8*)(x1bf + (size_t)(nt*16 + r)*8);

    // ---- stage 1: h1 tile via MFMA (K=32, zeros beyond k=6)
    f32x4 acc1[4];
    #pragma unroll
    for (int n4=0;n4<4;++n4) acc1[n4] = (f32x4){0.f,0.f,0.f,0.f};
    #pragma unroll
    for (int n4=0;n4<4;++n4)
      acc1[n4] = __builtin_amdgcn_mfma_f32_16x16x32_bf16(a1, W1B[n4], acc1[n4], 0, 0, 0);

    __syncthreads();   // prev iter's sh1 A-reads + epi store-reads complete
    unsigned* sh1u = (unsigned*)sh1;
    #pragma unroll
    for (int n4=0;n4<4;++n4){
      int c = 16*(4*w + n4) + r;
      #pragma unroll
      for (int j=0;j<4;++j){
        float v = fmaxf(acc1[n4][j] + b1r[n4], 0.f);
        unsigned mu = f2bf(v);
        unsigned ou = (unsigned)__shfl_xor((int)mu, 1);
        if (!(r & 1))
          sh1u[(4*g + j)*132 + (c>>1)] = mu | (ou<<16);
      }
    }
    __syncthreads();   // sh1 ready

    // ---- stage 2: yz = h1 @ W2
    f32x4 acc[4];
    #pragma unroll
    for (int n4=0;n4<4;++n4) acc[n4] = (f32x4){0.f,0.f,0.f,0.f};
    #pragma unroll
    for (int s=0;s<8;++s){
      short8 af = *(const short8*)(sh1 + r*264 + s*32 + 8*g);
      #pragma unroll
      for (int n4=0;n4<4;++n4)
        acc[n4] = __builtin_amdgcn_mfma_f32_16x16x32_bf16(af, B2[s][n4], acc[n4], 0, 0, 0);
    }
    __syncthreads();   // sh1 reads done; prev epi reads done

    // ---- epilogue: fp8 pack -> swizzled LDS
    #pragma unroll
    for (int n4=0;n4<4;++n4){
      int c = 16*(4*w + n4) + r;
      #pragma unroll
      for (int j=0;j<4;++j){
        int row = 4*g + j;
        unsigned b8 = f2fp8(acc[n4][j]);
        unsigned o1 = (unsigned)__shfl_xor((int)b8, 1);
        unsigned w01 = (b8 & 0xffu) | (o1<<8);
        unsigned o2 = (unsigned)__shfl_xor((int)w01, 2);
        if (!(r & 3)){
          int byte = (row*256 + c) ^ ((row & 7)<<4);
          *(unsigned*)(epi + byte) = (w01 & 0xffffu) | (o2<<16);
        }
      }
    }
    __syncthreads();   // epi ready

    // ---- stream out: y (cols 0-127) and z (cols 128-255), compact fp8
    {
      int row = tid>>4, seg = tid&15;
      int byte = (row*256 + seg*16) ^ ((row & 7)<<4);
      uint4 v = *(const uint4*)(epi + byte);
      if (seg < 8) *(uint4*)(ybuf + (size_t)tile*2048 + row*128 + seg*16) = v;
      else         *(uint4*)(zbuf + (size_t)tile*2048 + row*128 + (seg-8)*16) = v;
    }
    a1 = a1n;
    tile = nt;
  }
}

// ---- gather-aggregate + relu + mean pool: 2 edges/wave (half-wave each) ----
__global__ __launch_bounds__(256) void k_agg2(
    const unsigned char* __restrict__ ybuf, const unsigned char* __restrict__ zbuf,
    const int* __restrict__ csr, const int* __restrict__ offs, const int* __restrict__ cnt,
    const float* __restrict__ b2, float* __restrict__ partials){
  __shared__ float red[128];
  int tid = threadIdx.x;
  if (tid < 128) red[tid] = 0.f;
  __syncthreads();
  int lane = tid & 63, h = lane>>5, q = lane&31;
  int wave = blockIdx.x*4 + (tid>>6);
  const int nwaves = NB_AGG*4;
  float bb0 = b2[4*q], bb1 = b2[4*q+1], bb2 = b2[4*q+2], bb3 = b2[4*q+3];
  float p0=0.f, p1=0.f, p2=0.f, p3=0.f;
  const unsigned* y32 = (const unsigned*)ybuf;
  const unsigned* z32 = (const unsigned*)zbuf;

  for (int node = wave; node < N_NODES; node += nwaves){
    int off = offs[node], deg = cnt[node];
    float a0=0.f, a1=0.f, a2=0.f, a3=0.f;
    int e = 0;
    for (; e+2 <= deg; e += 2){
      int src = csr[off + e + h];
      unsigned u = y32[(size_t)src*32 + q];
      a0 += DEC_FP8(u,0); a1 += DEC_FP8(u,1); a2 += DEC_FP8(u,2); a3 += DEC_FP8(u,3);
    }
    if (e < deg && h == 0){
      int src = csr[off + e];
      unsigned u = y32[(size_t)src*32 + q];
      a0 += DEC_FP8(u,0); a1 += DEC_FP8(u,1); a2 += DEC_FP8(u,2); a3 += DEC_FP8(u,3);
    }
    a0 += __shfl_xor(a0, 32); a1 += __shfl_xor(a1, 32);
    a2 += __shfl_xor(a2, 32); a3 += __shfl_xor(a3, 32);
    float inv = 1.0f / (float)max(deg,1);
    unsigned uz = z32[(size_t)node*32 + q];
    if (h == 0){
      p0 += fmaxf(a0*inv + DEC_FP8(uz,0) + bb0, 0.f);
      p1 += fmaxf(a1*inv + DEC_FP8(uz,1) + bb1, 0.f);
      p2 += fmaxf(a2*inv + DEC_FP8(uz,2) + bb2, 0.f);
      p3 += fmaxf(a3*inv + DEC_FP8(uz,3) + bb3, 0.f);
    }
  }
  if (h == 0){
    atomicAdd(&red[4*q],   p0);
    atomicAdd(&red[4*q+1], p1);
    atomicAdd(&red[4*q+2], p2);
    atomicAdd(&red[4*q+3], p3);
  }
  __syncthreads();
  if (tid < 128) partials[(size_t)blockIdx.x*128 + tid] = red[tid];
}

// ---- reduce partials -> gsum ----------------------------------------------
__global__ void k_red(const float* __restrict__ partials, float* __restrict__ gsum){
  int t = threadIdx.x;  // 128
  float s = 0.f;
  for (int b = blockIdx.x; b < NB_AGG; b += 64) s += partials[(size_t)b*128 + t];
  atomicAdd(&gsum[t], s);
}

// ---- decoder + softmax + argmax -------------------------------------------
__global__ void k_dec(const float* __restrict__ gsum, const float* __restrict__ Wd,
                      const float* __restrict__ bd, float* __restrict__ out, int out_size){
  int lane = threadIdx.x;  // 64
  float l = -1e30f;
  if (lane < 10){
    float s = bd[lane];
    for (int k=0;k<128;++k) s += (gsum[k]*(1.0f/N_NODES)) * Wd[k*10 + lane];
    l = s;
  }
  float m = l;
  #pragma unroll
  for (int d=1; d<16; d<<=1) m = fmaxf(m, __shfl_xor(m, d));
  float e = (lane<10)? expf(l - m) : 0.f;
  float sum = e;
  #pragma unroll
  for (int d=1; d<16; d<<=1) sum += __shfl_xor(sum, d);
  float p = (lane<10)? e/sum : 0.f;
  if (lane < 10) out[lane] = p;
  float v = p; int idx = (lane<10)? lane : 1000;
  #pragma unroll
  for (int d=1; d<16; d<<=1){
    float ov = __shfl_xor(v, d); int oi = __shfl_xor(idx, d);
    if (ov > v || (ov == v && oi < idx)){ v = ov; idx = oi; }
  }
  if (lane == 0 && out_size > 10) out[10] = (float)idx;
}

// ---- launch ----------------------------------------------------------------
extern "C" void kernel_launch(void* const* d_in, const int* in_sizes, int n_in,
                              void* d_out, int out_size, void* d_ws, size_t ws_size,
                              hipStream_t stream){
  const float* pos = (const float*)d_in[0];
  const int*   face= (const int*)  d_in[1];
  const float* W1l = (const float*)d_in[2];
  const float* W1r = (const float*)d_in[3];
  const float* b1  = (const float*)d_in[4];
  const float* W2l = (const float*)d_in[5];
  const float* W2r = (const float*)d_in[6];
  const float* b2  = (const float*)d_in[7];
  const float* Wd  = (const float*)d_in[8];
  const float* bd  = (const float*)d_in[9];

  char* ws = (char*)d_ws;
  size_t o = 0;
  auto alloc = [&](size_t bytes){ size_t rr = o; o += (bytes + 1023) & ~(size_t)1023; return rr; };
  int*   bfill    = (int*)  (ws + alloc(NBUCKETS*4));            // zeroed
  float* gsum     = (float*)(ws + alloc(512));                   // zeroed
  size_t zero_len = o;
  int*   bbase    = (int*)  (ws + alloc(NBUCKETS*4));
  int*   offs     = (int*)  (ws + alloc((size_t)N_NODES*4));
  int*   cnt      = (int*)  (ws + alloc((size_t)N_NODES*4));
  int*   csr      = (int*)  (ws + alloc((size_t)N_EDGES*4));
  unsigned short* bprep = (unsigned short*)(ws + alloc(131072));
  unsigned short* w1p   = (unsigned short*)(ws + alloc(16384));
  unsigned short* x1bf  = (unsigned short*)(ws + alloc((size_t)N_NODES*8*2));
  unsigned char*  ybuf  = (unsigned char*)(ws + alloc((size_t)N_NODES*128));
  unsigned char*  zbuf  = (unsigned char*)(ws + alloc((size_t)N_NODES*128));
  int2*  pairs    = (int2*) (ws + alloc((size_t)NBUCKETS*CAP_BUCKET*8));
  float* partials = (float*)(ws + alloc((size_t)NB_AGG*128*4));

  hipMemsetAsync(ws, 0, zero_len, stream);

  k_bprep<<<256, 256, 0, stream>>>(W2l, W2r, bprep);
  k_w1prep<<<32, 256, 0, stream>>>(W1l, W1r, w1p);
  k_passA<<<NBUCKETS, 256, 0, stream>>>(face, bfill, pairs);
  k_bscan<<<1, 64, 0, stream>>>(bfill, bbase);
  k_passB<<<NBUCKETS, 512, 0, stream>>>(pairs, bfill, bbase, offs, cnt, csr);
  k_x1<<<(N_NODES+255)/256, 256, 0, stream>>>(pos, csr, offs, cnt, x1bf);
  k_mm<<<MM_BLOCKS, 256, 0, stream>>>(x1bf, w1p, b1, bprep, ybuf, zbuf);
  k_agg2<<<NB_AGG, 256, 0, stream>>>(ybuf, zbuf, csr, offs, cnt, b2, partials);
  k_red<<<64, 128, 0, stream>>>(partials, gsum);
  k_dec<<<1, 64, 0, stream>>>(gsum, Wd, bd, (float*)d_out, out_size);
}

// Round 10
// 286.557 us; speedup vs baseline: 1.1161x; 1.1161x over previous
//
#include <hip/hip_runtime.h>
#include <cstdint>
#include <cstddef>

#define N_NODES 200000
#define N_FACES 400000
#define N_EDGES (3*N_FACES)
#define NBUCKETS 196           // ceil(200000/1024), 1024 node-ids per bucket
#define CAP_BUCKET 8192        // mean 6144, sigma~101 -> +20 sigma margin
#define FACES_PER_BLK 2048
#define MM_BLOCKS 512          // 2 blocks/CU exactly; 12500 row-tiles of 16
#define N_TILES 12500
#define NB_AGG 2048            // agg2 blocks

typedef __attribute__((ext_vector_type(8))) short short8;
typedef __attribute__((ext_vector_type(4))) float f32x4;

__device__ __forceinline__ unsigned short f2bf(float f){
  unsigned u = __float_as_uint(f);
  u = u + 0x7fffu + ((u>>16)&1u);   // RNE
  return (unsigned short)(u>>16);
}

// ---- fp8 e4m3fn helpers ----------------------------------------------------
__device__ __forceinline__ unsigned f2fp8(float f){   // RNE encode (fallback)
  unsigned sgn = (__float_as_uint(f) >> 24) & 0x80u;
  float a = fabsf(f);
  a = fminf(a, 448.f);
  unsigned out;
  if (a < 0.015625f){
    out = (unsigned)__float2int_rn(a * 512.f);        // subnormal, 0..8
  } else {
    unsigned m = __float_as_uint(a);
    m = m + 0xFFFFFu + ((m >> 20) & 1u);              // RNE at 3 mantissa bits
    int e = (int)(m >> 23) - 127;                     // -6..8
    out = ((unsigned)(e + 7) << 3) | ((m >> 20) & 7u);
  }
  return out | sgn;
}
__device__ __forceinline__ float fp8tof(unsigned b){  // exact decode (incl subnormals)
  unsigned t = ((b & 0x80u) << 24) | ((b & 0x7fu) << 20);
  return __uint_as_float(t) * 0x1p120f;
}
#if __has_builtin(__builtin_amdgcn_cvt_f32_fp8)
#define DEC_FP8(u, i) __builtin_amdgcn_cvt_f32_fp8((int)(u), (i))
#else
#define DEC_FP8(u, i) fp8tof(((u) >> ((i)*8)) & 0xffu)
#endif
__device__ __forceinline__ unsigned pk_fp8(float a, float b){  // 2 floats -> 2 fp8 bytes
#if __has_builtin(__builtin_amdgcn_cvt_pk_fp8_f32)
  return (unsigned)__builtin_amdgcn_cvt_pk_fp8_f32(a, b, 0, false) & 0xffffu;
#else
  return f2fp8(a) | (f2fp8(b) << 8);
#endif
}

// ---- CSR build, pass A: bin (src,dst) pairs by dst>>10 ---------------------
__global__ __launch_bounds__(256) void k_passA(const int* __restrict__ face,
                                               int* __restrict__ bfill,
                                               int2* __restrict__ pairs){
  __shared__ int hist[NBUCKETS], basel[NBUCKETS], rank[NBUCKETS];
  int tid = threadIdx.x;
  if (tid < NBUCKETS) hist[tid] = 0;
  __syncthreads();
  int f0 = blockIdx.x * FACES_PER_BLK + tid;
  int v0[8], v1[8], v2[8];
  #pragma unroll
  for (int k=0;k<8;++k){
    int f = f0 + k*256;
    if (f < N_FACES){
      v0[k] = face[f]; v1[k] = face[f + N_FACES]; v2[k] = face[f + 2*N_FACES];
    } else { v0[k] = 0; v1[k] = 0; v2[k] = 0; }
  }
  #pragma unroll
  for (int k=0;k<8;++k){
    if (v0[k] != v1[k]) atomicAdd(&hist[v1[k]>>10], 1);
    if (v1[k] != v2[k]) atomicAdd(&hist[v2[k]>>10], 1);
    if (v0[k] != v2[k]) atomicAdd(&hist[v2[k]>>10], 1);
  }
  __syncthreads();
  if (tid < NBUCKETS){
    basel[tid] = atomicAdd(&bfill[tid], hist[tid]);
    rank[tid] = 0;
  }
  __syncthreads();
  #pragma unroll
  for (int k=0;k<8;++k){
    if (v0[k] != v1[k]){
      int b = v1[k]>>10;
      int p = basel[b] + atomicAdd(&rank[b],1);
      if (p < CAP_BUCKET) pairs[(size_t)b*CAP_BUCKET + p] = make_int2(v0[k], v1[k]);
    }
    if (v1[k] != v2[k]){
      int b = v2[k]>>10;
      int p = basel[b] + atomicAdd(&rank[b],1);
      if (p < CAP_BUCKET) pairs[(size_t)b*CAP_BUCKET + p] = make_int2(v1[k], v2[k]);
    }
    if (v0[k] != v2[k]){
      int b = v2[k]>>10;
      int p = basel[b] + atomicAdd(&rank[b],1);
      if (p < CAP_BUCKET) pairs[(size_t)b*CAP_BUCKET + p] = make_int2(v0[k], v2[k]);
    }
  }
}

// ---- exclusive scan of the 196 bucket fills (one wave) ---------------------
__global__ void k_bscan(const int* __restrict__ bfill, int* __restrict__ bbase){
  int l = threadIdx.x;  // 64
  int v[4]; int s = 0;
  #pragma unroll
  for (int k=0;k<4;++k){ int i = l*4+k; v[k] = (i < NBUCKETS)? min(bfill[i], CAP_BUCKET) : 0; s += v[k]; }
  int inc = s;
  #pragma unroll
  for (int d=1; d<64; d<<=1){ int t = __shfl_up(inc, d); if (l >= d) inc += t; }
  int pre = inc - s;
  #pragma unroll
  for (int k=0;k<4;++k){ int i = l*4+k; if (i < NBUCKETS) bbase[i] = pre; pre += v[k]; }
}

// ---- CSR build, pass B: per-bucket LDS counting sort -----------------------
__global__ __launch_bounds__(512) void k_passB(const int2* __restrict__ pairs,
                                               const int* __restrict__ bfill,
                                               const int* __restrict__ bbase,
                                               int* __restrict__ offs, int* __restrict__ cnt,
                                               int* __restrict__ csr){
  __shared__ int lcnt[1024], lfill[1024], sc[512];
  __shared__ int lcsr[CAP_BUCKET];
  int b = blockIdx.x, tid = threadIdx.x;
  int nb = min(bfill[b], CAP_BUCKET);
  int base = bbase[b];
  const int2* bp = pairs + (size_t)b*CAP_BUCKET;
  lcnt[tid] = 0; lcnt[tid+512] = 0;
  __syncthreads();
  for (int i = tid; i < nb; i += 512){
    int2 e = bp[i];
    atomicAdd(&lcnt[e.y & 1023], 1);
  }
  __syncthreads();
  int c0 = lcnt[2*tid], c1 = lcnt[2*tid+1];
  int s = c0 + c1;
  sc[tid] = s; __syncthreads();
  for (int d=1; d<512; d<<=1){
    int v = (tid>=d)? sc[tid-d] : 0; __syncthreads();
    sc[tid] += v; __syncthreads();
  }
  int excl = sc[tid] - s;
  lfill[2*tid] = excl; lfill[2*tid+1] = excl + c0;
  int g0 = b*1024 + 2*tid, g1 = g0 + 1;
  if (g0 < N_NODES){ offs[g0] = base + excl;      cnt[g0] = c0; }
  if (g1 < N_NODES){ offs[g1] = base + excl + c0; cnt[g1] = c1; }
  __syncthreads();
  for (int i = tid; i < nb; i += 512){
    int2 e = bp[i];
    int p = atomicAdd(&lfill[e.y & 1023], 1);
    lcsr[p] = e.x;
  }
  __syncthreads();
  for (int i = tid; i < nb; i += 512){
    csr[base + i] = lcsr[i];
  }
}

// ---- stage-2 B pre-pack: [W2l|W2r] (256K x 256N) into MFMA fragment order --
// bp[((s*16+n)*64+l)*8+j] = Bstack[32s+8*(l>>4)+j][16n+(l&15)]
__global__ void k_bprep(const float* __restrict__ W2l, const float* __restrict__ W2r,
                        unsigned short* __restrict__ bp){
  int idx = blockIdx.x*256 + threadIdx.x;   // 65536 total
  int j = idx & 7, l = (idx>>3)&63, n = (idx>>9)&15, s = idx>>13;
  int k = 32*s + 8*(l>>4) + j;
  int c = 16*n + (l&15);
  float v = (c < 128)? W2l[k*128 + c] : W2r[k*128 + (c-128)];
  bp[idx] = f2bf(v);
}

// ---- stage-1 B pre-pack: [W1l;W1r] (6 x 256) K-padded to 32, frag order ----
__global__ void k_w1prep(const float* __restrict__ W1l, const float* __restrict__ W1r,
                         unsigned short* __restrict__ w1p){
  int idx = blockIdx.x*256 + threadIdx.x;   // 8192 total
  int j = idx & 7, l = (idx>>3)&63, n = idx>>9;   // n in [0,16)
  int k = 8*(l>>4) + j;
  int c = 16*n + (l&15);
  float v = 0.f;
  if (k < 3) v = W1l[k*256 + c];
  else if (k < 6) v = W1r[(k-3)*256 + c];
  w1p[idx] = f2bf(v);
}

// ---- x1: per node, mean of neighbor pos + own pos, packed bf16 [8] --------
__global__ void k_x1(const float* __restrict__ pos, const int* __restrict__ csr,
                     const int* __restrict__ offs, const int* __restrict__ cnt,
                     unsigned short* __restrict__ x1bf){
  int i = blockIdx.x*256 + threadIdx.x;
  if (i >= N_NODES) return;
  int off = offs[i], deg = cnt[i];
  float s0=0.f, s1=0.f, s2=0.f;
  int e = 0;
  for (; e+2 <= deg; e += 2){
    int a = csr[off+e], b = csr[off+e+1];
    const float* pa = pos + 3*a; const float* pb = pos + 3*b;
    s0 += pa[0] + pb[0]; s1 += pa[1] + pb[1]; s2 += pa[2] + pb[2];
  }
  if (e < deg){
    const float* pa = pos + 3*csr[off+e];
    s0 += pa[0]; s1 += pa[1]; s2 += pa[2];
  }
  float inv = 1.0f / (float)max(deg,1);
  float p0 = pos[3*i], p1 = pos[3*i+1], p2 = pos[3*i+2];
  uint4 pk;
  pk.x = (unsigned)f2bf(s0*inv) | ((unsigned)f2bf(s1*inv)<<16);
  pk.y = (unsigned)f2bf(s2*inv) | ((unsigned)f2bf(p0)<<16);
  pk.z = (unsigned)f2bf(p1)     | ((unsigned)f2bf(p2)<<16);
  pk.w = 0;
  *(uint4*)(x1bf + (size_t)i*8) = pk;
}

// ---- fused double GEMM, 1-barrier software pipeline ------------------------
// stage2 consumes sh1[cur] while stage1 produces sh1[cur^1] for the NEXT tile;
// single __syncthreads per iter covers both visibility and reuse.
__global__ __launch_bounds__(256,2) void k_mm(
    const unsigned short* __restrict__ x1bf,
    const unsigned short* __restrict__ w1p,
    const float* __restrict__ b1,
    const unsigned short* __restrict__ bp,
    unsigned char* __restrict__ ybuf,
    unsigned char* __restrict__ zbuf){
  __shared__ unsigned short sh1[2][16*264];   // 2 x 8.25 KB, 528B row stride
  __shared__ unsigned Sl[1024];               // 4 KB: per-wave 256-uint slice
  int tid = threadIdx.x;
  int w = tid>>6, lane = tid&63, r = lane&15, g = lane>>4;

  // stage-2 B frags (cols 64w..64w+64), held whole kernel
  short8 B2[8][4];
  #pragma unroll
  for (int s=0;s<8;++s)
    #pragma unroll
    for (int n4=0;n4<4;++n4)
      B2[s][n4] = *(const short8*)(bp + ((size_t)((s*16 + 4*w + n4)*64 + lane))*8);
  // stage-1 B frags + bias
  short8 W1B[4];
  float b1r[4];
  #pragma unroll
  for (int n4=0;n4<4;++n4){
    W1B[n4] = *(const short8*)(w1p + ((size_t)((4*w + n4)*64 + lane))*8);
    b1r[n4] = b1[16*(4*w + n4) + r];
  }

  int tile = blockIdx.x;
  // ---- prologue: stage1 for first tile -> sh1[0]
  {
    short8 a1 = {0,0,0,0,0,0,0,0};
    if (g == 0) a1 = *(const short8*)(x1bf + (size_t)(tile*16 + r)*8);
    f32x4 acc1[4];
    #pragma unroll
    for (int n4=0;n4<4;++n4) acc1[n4] = (f32x4){0.f,0.f,0.f,0.f};
    #pragma unroll
    for (int n4=0;n4<4;++n4)
      acc1[n4] = __builtin_amdgcn_mfma_f32_16x16x32_bf16(a1, W1B[n4], acc1[n4], 0, 0, 0);
    unsigned* sh1u = (unsigned*)sh1[0];
    #pragma unroll
    for (int n4=0;n4<4;++n4){
      int c = 16*(4*w + n4) + r;
      #pragma unroll
      for (int j=0;j<4;++j){
        float v = fmaxf(acc1[n4][j] + b1r[n4], 0.f);
        unsigned mu = f2bf(v);
        unsigned ou = (unsigned)__shfl_xor((int)mu, 1);
        if (!(r & 1)) sh1u[(4*g + j)*132 + (c>>1)] = mu | (ou<<16);
      }
    }
  }
  __syncthreads();
  int cur = 0;

  while (tile < N_TILES){
    int nt = tile + MM_BLOCKS;
    short8 a1n = {0,0,0,0,0,0,0,0};
    if (nt < N_TILES && g == 0)
      a1n = *(const short8*)(x1bf + (size_t)(nt*16 + r)*8);

    // ---- stage 2: yz(tile) = h1 @ W2, from sh1[cur]
    f32x4 acc[4];
    #pragma unroll
    for (int n4=0;n4<4;++n4) acc[n4] = (f32x4){0.f,0.f,0.f,0.f};
    #pragma unroll
    for (int s=0;s<8;++s){
      short8 af = *(const short8*)(sh1[cur] + r*264 + s*32 + 8*g);
      #pragma unroll
      for (int n4=0;n4<4;++n4)
        acc[n4] = __builtin_amdgcn_mfma_f32_16x16x32_bf16(af, B2[s][n4], acc[n4], 0, 0, 0);
    }

    // ---- stage 1 for NEXT tile -> sh1[cur^1] (independent of stage 2)
    if (nt < N_TILES){
      f32x4 acc1[4];
      #pragma unroll
      for (int n4=0;n4<4;++n4) acc1[n4] = (f32x4){0.f,0.f,0.f,0.f};
      #pragma unroll
      for (int n4=0;n4<4;++n4)
        acc1[n4] = __builtin_amdgcn_mfma_f32_16x16x32_bf16(a1n, W1B[n4], acc1[n4], 0, 0, 0);
      unsigned* sh1u = (unsigned*)sh1[cur^1];
      #pragma unroll
      for (int n4=0;n4<4;++n4){
        int c = 16*(4*w + n4) + r;
        #pragma unroll
        for (int j=0;j<4;++j){
          float v = fmaxf(acc1[n4][j] + b1r[n4], 0.f);
          unsigned mu = f2bf(v);
          unsigned ou = (unsigned)__shfl_xor((int)mu, 1);
          if (!(r & 1)) sh1u[(4*g + j)*132 + (c>>1)] = mu | (ou<<16);
        }
      }
    }

    // ---- epilogue: fp8 pack into wave-private LDS slice (no barrier needed)
    #pragma unroll
    for (int n4=0;n4<4;++n4){
      #pragma unroll
      for (int j=0;j<4;++j){
        float v0 = acc[n4][j];
        float v1 = __shfl_xor(v0, 1);
        unsigned p16 = pk_fp8(v0, v1);               // cols (r, r+1), even r lanes
        unsigned hi  = (unsigned)__shfl_xor((int)p16, 2);
        if (!(r & 3))
          Sl[w*256 + (4*g + j)*16 + 4*n4 + (r>>2)] = (p16 & 0xffffu) | (hi<<16);
      }
    }
    // stream own slice out: 16 rows x 64 cols fp8 per wave, coalesced
    {
      const uint4* sl4 = (const uint4*)(Sl + w*256);
      uint4 v = sl4[lane];
      int row = lane>>2, u4 = lane&3;
      size_t rowg = (size_t)tile*16 + row;
      if (w < 2) *(uint4*)(ybuf + rowg*128 + w*64     + u4*16) = v;
      else       *(uint4*)(zbuf + rowg*128 + (w-2)*64 + u4*16) = v;
    }
    __syncthreads();   // sh1[cur^1] visible; sh1[cur] reads drained
    cur ^= 1;
    tile = nt;
  }
}

// ---- gather-aggregate + relu + mean pool: 2 edges/wave (half-wave each) ----
__global__ __launch_bounds__(256) void k_agg2(
    const unsigned char* __restrict__ ybuf, const unsigned char* __restrict__ zbuf,
    const int* __restrict__ csr, const int* __restrict__ offs, const int* __restrict__ cnt,
    const float* __restrict__ b2, float* __restrict__ partials){
  __shared__ float red[128];
  int tid = threadIdx.x;
  if (tid < 128) red[tid] = 0.f;
  __syncthreads();
  int lane = tid & 63, h = lane>>5, q = lane&31;
  int wave = blockIdx.x*4 + (tid>>6);
  const int nwaves = NB_AGG*4;
  float bb0 = b2[4*q], bb1 = b2[4*q+1], bb2 = b2[4*q+2], bb3 = b2[4*q+3];
  float p0=0.f, p1=0.f, p2=0.f, p3=0.f;
  const unsigned* y32 = (const unsigned*)ybuf;
  const unsigned* z32 = (const unsigned*)zbuf;

  for (int node = wave; node < N_NODES; node += nwaves){
    int off = offs[node], deg = cnt[node];
    float a0=0.f, a1=0.f, a2=0.f, a3=0.f;
    int e = 0;
    for (; e+2 <= deg; e += 2){
      int src = csr[off + e + h];
      unsigned u = y32[(size_t)src*32 + q];
      a0 += DEC_FP8(u,0); a1 += DEC_FP8(u,1); a2 += DEC_FP8(u,2); a3 += DEC_FP8(u,3);
    }
    if (e < deg && h == 0){
      int src = csr[off + e];
      unsigned u = y32[(size_t)src*32 + q];
      a0 += DEC_FP8(u,0); a1 += DEC_FP8(u,1); a2 += DEC_FP8(u,2); a3 += DEC_FP8(u,3);
    }
    a0 += __shfl_xor(a0, 32); a1 += __shfl_xor(a1, 32);
    a2 += __shfl_xor(a2, 32); a3 += __shfl_xor(a3, 32);
    float inv = 1.0f / (float)max(deg,1);
    unsigned uz = z32[(size_t)node*32 + q];
    if (h == 0){
      p0 += fmaxf(a0*inv + DEC_FP8(uz,0) + bb0, 0.f);
      p1 += fmaxf(a1*inv + DEC_FP8(uz,1) + bb1, 0.f);
      p2 += fmaxf(a2*inv + DEC_FP8(uz,2) + bb2, 0.f);
      p3 += fmaxf(a3*inv + DEC_FP8(uz,3) + bb3, 0.f);
    }
  }
  if (h == 0){
    atomicAdd(&red[4*q],   p0);
    atomicAdd(&red[4*q+1], p1);
    atomicAdd(&red[4*q+2], p2);
    atomicAdd(&red[4*q+3], p3);
  }
  __syncthreads();
  if (tid < 128) partials[(size_t)blockIdx.x*128 + tid] = red[tid];
}

// ---- reduce partials -> gsum ----------------------------------------------
__global__ void k_red(const float* __restrict__ partials, float* __restrict__ gsum){
  int t = threadIdx.x;  // 128
  float s = 0.f;
  for (int b = blockIdx.x; b < NB_AGG; b += 64) s += partials[(size_t)b*128 + t];
  atomicAdd(&gsum[t], s);
}

// ---- decoder + softmax + argmax -------------------------------------------
__global__ void k_dec(const float* __restrict__ gsum, const float* __restrict__ Wd,
                      const float* __restrict__ bd, float* __restrict__ out, int out_size){
  int lane = threadIdx.x;  // 64
  float l = -1e30f;
  if (lane < 10){
    float s = bd[lane];
    for (int k=0;k<128;++k) s += (gsum[k]*(1.0f/N_NODES)) * Wd[k*10 + lane];
    l = s;
  }
  float m = l;
  #pragma unroll
  for (int d=1; d<16; d<<=1) m = fmaxf(m, __shfl_xor(m, d));
  float e = (lane<10)? expf(l - m) : 0.f;
  float sum = e;
  #pragma unroll
  for (int d=1; d<16; d<<=1) sum += __shfl_xor(sum, d);
  float p = (lane<10)? e/sum : 0.f;
  if (lane < 10) out[lane] = p;
  float v = p; int idx = (lane<10)? lane : 1000;
  #pragma unroll
  for (int d=1; d<16; d<<=1){
    float ov = __shfl_xor(v, d); int oi = __shfl_xor(idx, d);
    if (ov > v || (ov == v && oi < idx)){ v = ov; idx = oi; }
  }
  if (lane == 0 && out_size > 10) out[10] = (float)idx;
}

// ---- launch ----------------------------------------------------------------
extern "C" void kernel_launch(void* const* d_in, const int* in_sizes, int n_in,
                              void* d_out, int out_size, void* d_ws, size_t ws_size,
                              hipStream_t stream){
  const float* pos = (const float*)d_in[0];
  const int*   face= (const int*)  d_in[1];
  const float* W1l = (const float*)d_in[2];
  const float* W1r = (const float*)d_in[3];
  const float* b1  = (const float*)d_in[4];
  const float* W2l = (const float*)d_in[5];
  const float* W2r = (const float*)d_in[6];
  const float* b2  = (const float*)d_in[7];
  const float* Wd  = (const float*)d_in[8];
  const float* bd  = (const float*)d_in[9];

  char* ws = (char*)d_ws;
  size_t o = 0;
  auto alloc = [&](size_t bytes){ size_t rr = o; o += (bytes + 1023) & ~(size_t)1023; return rr; };
  int*   bfill    = (int*)  (ws + alloc(NBUCKETS*4));            // zeroed
  float* gsum     = (float*)(ws + alloc(512));                   // zeroed
  size_t zero_len = o;
  int*   bbase    = (int*)  (ws + alloc(NBUCKETS*4));
  int*   offs     = (int*)  (ws + alloc((size_t)N_NODES*4));
  int*   cnt      = (int*)  (ws + alloc((size_t)N_NODES*4));
  int*   csr      = (int*)  (ws + alloc((size_t)N_EDGES*4));
  unsigned short* bprep = (unsigned short*)(ws + alloc(131072));
  unsigned short* w1p   = (unsigned short*)(ws + alloc(16384));
  unsigned short* x1bf  = (unsigned short*)(ws + alloc((size_t)N_NODES*8*2));
  unsigned char*  ybuf  = (unsigned char*)(ws + alloc((size_t)N_NODES*128));
  unsigned char*  zbuf  = (unsigned char*)(ws + alloc((size_t)N_NODES*128));
  int2*  pairs    = (int2*) (ws + alloc((size_t)NBUCKETS*CAP_BUCKET*8));
  float* partials = (float*)(ws + alloc((size_t)NB_AGG*128*4));

  hipMemsetAsync(ws, 0, zero_len, stream);

  k_bprep<<<256, 256, 0, stream>>>(W2l, W2r, bprep);
  k_w1prep<<<32, 256, 0, stream>>>(W1l, W1r, w1p);
  k_passA<<<NBUCKETS, 256, 0, stream>>>(face, bfill, pairs);
  k_bscan<<<1, 64, 0, stream>>>(bfill, bbase);
  k_passB<<<NBUCKETS, 512, 0, stream>>>(pairs, bfill, bbase, offs, cnt, csr);
  k_x1<<<(N_NODES+255)/256, 256, 0, stream>>>(pos, csr, offs, cnt, x1bf);
  k_mm<<<MM_BLOCKS, 256, 0, stream>>>(x1bf, w1p, b1, bprep, ybuf, zbuf);
  k_agg2<<<NB_AGG, 256, 0, stream>>>(ybuf, zbuf, csr, offs, cnt, b2, partials);
  k_red<<<64, 128, 0, stream>>>(partials, gsum);
  k_dec<<<1, 64, 0, stream>>>(gsum, Wd, bd, (float*)d_out, out_size);
}

// Round 11
// 270.103 us; speedup vs baseline: 1.1841x; 1.0609x over previous
//
#include <hip/hip_runtime.h>
#include <cstdint>
#include <cstddef>

#define N_NODES 200000
#define N_FACES 400000
#define N_EDGES (3*N_FACES)
#define NBUCKETS 196           // ceil(200000/1024), 1024 node-ids per bucket
#define CAP_BUCKET 8192        // mean 6144, sigma~101 -> +20 sigma margin
#define FACES_PER_BLK 2048
#define MM_BLOCKS 512          // 2 blocks/CU exactly; 12500 row-tiles of 16
#define N_TILES 12500
#define NB_AGG 2048            // agg2 blocks

typedef __attribute__((ext_vector_type(8))) short short8;
typedef __attribute__((ext_vector_type(4))) float f32x4;

__device__ __forceinline__ unsigned short f2bf(float f){
  unsigned u = __float_as_uint(f);
  u = u + 0x7fffu + ((u>>16)&1u);   // RNE
  return (unsigned short)(u>>16);
}

// ---- fp8 e4m3fn helpers ----------------------------------------------------
__device__ __forceinline__ unsigned f2fp8(float f){   // RNE encode (fallback)
  unsigned sgn = (__float_as_uint(f) >> 24) & 0x80u;
  float a = fabsf(f);
  a = fminf(a, 448.f);
  unsigned out;
  if (a < 0.015625f){
    out = (unsigned)__float2int_rn(a * 512.f);        // subnormal, 0..8
  } else {
    unsigned m = __float_as_uint(a);
    m = m + 0xFFFFFu + ((m >> 20) & 1u);              // RNE at 3 mantissa bits
    int e = (int)(m >> 23) - 127;                     // -6..8
    out = ((unsigned)(e + 7) << 3) | ((m >> 20) & 7u);
  }
  return out | sgn;
}
__device__ __forceinline__ float fp8tof(unsigned b){  // exact decode (incl subnormals)
  unsigned t = ((b & 0x80u) << 24) | ((b & 0x7fu) << 20);
  return __uint_as_float(t) * 0x1p120f;
}
#if __has_builtin(__builtin_amdgcn_cvt_f32_fp8)
#define DEC_FP8(u, i) __builtin_amdgcn_cvt_f32_fp8((int)(u), (i))
#else
#define DEC_FP8(u, i) fp8tof(((u) >> ((i)*8)) & 0xffu)
#endif
__device__ __forceinline__ unsigned pk_fp8(float a, float b){  // 2 floats -> 2 fp8 bytes
#if __has_builtin(__builtin_amdgcn_cvt_pk_fp8_f32)
  return (unsigned)__builtin_amdgcn_cvt_pk_fp8_f32(a, b, 0, false) & 0xffffu;
#else
  return f2fp8(a) | (f2fp8(b) << 8);
#endif
}

// ---- CSR build, pass A: bin (src,dst) pairs by dst>>10 ---------------------
__global__ __launch_bounds__(256) void k_passA(const int* __restrict__ face,
                                               int* __restrict__ bfill,
                                               int2* __restrict__ pairs){
  __shared__ int hist[NBUCKETS], basel[NBUCKETS], rank[NBUCKETS];
  int tid = threadIdx.x;
  if (tid < NBUCKETS) hist[tid] = 0;
  __syncthreads();
  int f0 = blockIdx.x * FACES_PER_BLK + tid;
  int v0[8], v1[8], v2[8];
  #pragma unroll
  for (int k=0;k<8;++k){
    int f = f0 + k*256;
    if (f < N_FACES){
      v0[k] = face[f]; v1[k] = face[f + N_FACES]; v2[k] = face[f + 2*N_FACES];
    } else { v0[k] = 0; v1[k] = 0; v2[k] = 0; }
  }
  #pragma unroll
  for (int k=0;k<8;++k){
    if (v0[k] != v1[k]) atomicAdd(&hist[v1[k]>>10], 1);
    if (v1[k] != v2[k]) atomicAdd(&hist[v2[k]>>10], 1);
    if (v0[k] != v2[k]) atomicAdd(&hist[v2[k]>>10], 1);
  }
  __syncthreads();
  if (tid < NBUCKETS){
    basel[tid] = atomicAdd(&bfill[tid], hist[tid]);
    rank[tid] = 0;
  }
  __syncthreads();
  #pragma unroll
  for (int k=0;k<8;++k){
    if (v0[k] != v1[k]){
      int b = v1[k]>>10;
      int p = basel[b] + atomicAdd(&rank[b],1);
      if (p < CAP_BUCKET) pairs[(size_t)b*CAP_BUCKET + p] = make_int2(v0[k], v1[k]);
    }
    if (v1[k] != v2[k]){
      int b = v2[k]>>10;
      int p = basel[b] + atomicAdd(&rank[b],1);
      if (p < CAP_BUCKET) pairs[(size_t)b*CAP_BUCKET + p] = make_int2(v1[k], v2[k]);
    }
    if (v0[k] != v2[k]){
      int b = v2[k]>>10;
      int p = basel[b] + atomicAdd(&rank[b],1);
      if (p < CAP_BUCKET) pairs[(size_t)b*CAP_BUCKET + p] = make_int2(v0[k], v2[k]);
    }
  }
}

// ---- exclusive scan of the 196 bucket fills (one wave) ---------------------
__global__ void k_bscan(const int* __restrict__ bfill, int* __restrict__ bbase){
  int l = threadIdx.x;  // 64
  int v[4]; int s = 0;
  #pragma unroll
  for (int k=0;k<4;++k){ int i = l*4+k; v[k] = (i < NBUCKETS)? min(bfill[i], CAP_BUCKET) : 0; s += v[k]; }
  int inc = s;
  #pragma unroll
  for (int d=1; d<64; d<<=1){ int t = __shfl_up(inc, d); if (l >= d) inc += t; }
  int pre = inc - s;
  #pragma unroll
  for (int k=0;k<4;++k){ int i = l*4+k; if (i < NBUCKETS) bbase[i] = pre; pre += v[k]; }
}

// ---- CSR build, pass B: per-bucket LDS counting sort -----------------------
__global__ __launch_bounds__(512) void k_passB(const int2* __restrict__ pairs,
                                               const int* __restrict__ bfill,
                                               const int* __restrict__ bbase,
                                               int* __restrict__ offs, int* __restrict__ cnt,
                                               int* __restrict__ csr){
  __shared__ int lcnt[1024], lfill[1024], sc[512];
  __shared__ int lcsr[CAP_BUCKET];
  int b = blockIdx.x, tid = threadIdx.x;
  int nb = min(bfill[b], CAP_BUCKET);
  int base = bbase[b];
  const int2* bp = pairs + (size_t)b*CAP_BUCKET;
  lcnt[tid] = 0; lcnt[tid+512] = 0;
  __syncthreads();
  for (int i = tid; i < nb; i += 512){
    int2 e = bp[i];
    atomicAdd(&lcnt[e.y & 1023], 1);
  }
  __syncthreads();
  int c0 = lcnt[2*tid], c1 = lcnt[2*tid+1];
  int s = c0 + c1;
  sc[tid] = s; __syncthreads();
  for (int d=1; d<512; d<<=1){
    int v = (tid>=d)? sc[tid-d] : 0; __syncthreads();
    sc[tid] += v; __syncthreads();
  }
  int excl = sc[tid] - s;
  lfill[2*tid] = excl; lfill[2*tid+1] = excl + c0;
  int g0 = b*1024 + 2*tid, g1 = g0 + 1;
  if (g0 < N_NODES){ offs[g0] = base + excl;      cnt[g0] = c0; }
  if (g1 < N_NODES){ offs[g1] = base + excl + c0; cnt[g1] = c1; }
  __syncthreads();
  for (int i = tid; i < nb; i += 512){
    int2 e = bp[i];
    int p = atomicAdd(&lfill[e.y & 1023], 1);
    lcsr[p] = e.x;
  }
  __syncthreads();
  for (int i = tid; i < nb; i += 512){
    csr[base + i] = lcsr[i];
  }
}

// ---- stage-2 B pre-pack: [W2l|W2r] (256K x 256N) into MFMA fragment order --
// bp[((s*16+n)*64+l)*8+j] = Bstack[32s+8*(l>>4)+j][16n+(l&15)]
__global__ void k_bprep(const float* __restrict__ W2l, const float* __restrict__ W2r,
                        unsigned short* __restrict__ bp){
  int idx = blockIdx.x*256 + threadIdx.x;   // 65536 total
  int j = idx & 7, l = (idx>>3)&63, n = (idx>>9)&15, s = idx>>13;
  int k = 32*s + 8*(l>>4) + j;
  int c = 16*n + (l&15);
  float v = (c < 128)? W2l[k*128 + c] : W2r[k*128 + (c-128)];
  bp[idx] = f2bf(v);
}

// ---- stage-1 B pre-pack: [W1l;W1r] (6 x 256) K-padded to 32, frag order ----
__global__ void k_w1prep(const float* __restrict__ W1l, const float* __restrict__ W1r,
                         unsigned short* __restrict__ w1p){
  int idx = blockIdx.x*256 + threadIdx.x;   // 8192 total
  int j = idx & 7, l = (idx>>3)&63, n = idx>>9;   // n in [0,16)
  int k = 8*(l>>4) + j;
  int c = 16*n + (l&15);
  float v = 0.f;
  if (k < 3) v = W1l[k*256 + c];
  else if (k < 6) v = W1r[(k-3)*256 + c];
  w1p[idx] = f2bf(v);
}

// ---- x1: per node, mean of neighbor pos + own pos, packed bf16 [8] --------
__global__ void k_x1(const float* __restrict__ pos, const int* __restrict__ csr,
                     const int* __restrict__ offs, const int* __restrict__ cnt,
                     unsigned short* __restrict__ x1bf){
  int i = blockIdx.x*256 + threadIdx.x;
  if (i >= N_NODES) return;
  int off = offs[i], deg = cnt[i];
  float s0=0.f, s1=0.f, s2=0.f;
  int e = 0;
  for (; e+2 <= deg; e += 2){
    int a = csr[off+e], b = csr[off+e+1];
    const float* pa = pos + 3*a; const float* pb = pos + 3*b;
    s0 += pa[0] + pb[0]; s1 += pa[1] + pb[1]; s2 += pa[2] + pb[2];
  }
  if (e < deg){
    const float* pa = pos + 3*csr[off+e];
    s0 += pa[0]; s1 += pa[1]; s2 += pa[2];
  }
  float inv = 1.0f / (float)max(deg,1);
  float p0 = pos[3*i], p1 = pos[3*i+1], p2 = pos[3*i+2];
  uint4 pk;
  pk.x = (unsigned)f2bf(s0*inv) | ((unsigned)f2bf(s1*inv)<<16);
  pk.y = (unsigned)f2bf(s2*inv) | ((unsigned)f2bf(p0)<<16);
  pk.z = (unsigned)f2bf(p1)     | ((unsigned)f2bf(p2)<<16);
  pk.w = 0;
  *(uint4*)(x1bf + (size_t)i*8) = pk;
}

// ---- fused double GEMM, 1-barrier software pipeline ------------------------
// stage2 consumes sh1[cur] while stage1 produces sh1[cur^1] for the NEXT tile;
// single __syncthreads per iter covers both visibility and reuse.
__global__ __launch_bounds__(256,2) void k_mm(
    const unsigned short* __restrict__ x1bf,
    const unsigned short* __restrict__ w1p,
    const float* __restrict__ b1,
    const unsigned short* __restrict__ bp,
    unsigned char* __restrict__ ybuf,
    unsigned char* __restrict__ zbuf){
  __shared__ unsigned short sh1[2][16*264];   // 2 x 8.25 KB, 528B row stride
  __shared__ unsigned Sl[1024];               // 4 KB: per-wave 256-uint slice
  int tid = threadIdx.x;
  int w = tid>>6, lane = tid&63, r = lane&15, g = lane>>4;

  // stage-2 B frags (cols 64w..64w+64), held whole kernel
  short8 B2[8][4];
  #pragma unroll
  for (int s=0;s<8;++s)
    #pragma unroll
    for (int n4=0;n4<4;++n4)
      B2[s][n4] = *(const short8*)(bp + ((size_t)((s*16 + 4*w + n4)*64 + lane))*8);
  // stage-1 B frags + bias
  short8 W1B[4];
  float b1r[4];
  #pragma unroll
  for (int n4=0;n4<4;++n4){
    W1B[n4] = *(const short8*)(w1p + ((size_t)((4*w + n4)*64 + lane))*8);
    b1r[n4] = b1[16*(4*w + n4) + r];
  }

  int tile = blockIdx.x;
  // ---- prologue: stage1 for first tile -> sh1[0]
  {
    short8 a1 = {0,0,0,0,0,0,0,0};
    if (g == 0) a1 = *(const short8*)(x1bf + (size_t)(tile*16 + r)*8);
    f32x4 acc1[4];
    #pragma unroll
    for (int n4=0;n4<4;++n4) acc1[n4] = (f32x4){0.f,0.f,0.f,0.f};
    #pragma unroll
    for (int n4=0;n4<4;++n4)
      acc1[n4] = __builtin_amdgcn_mfma_f32_16x16x32_bf16(a1, W1B[n4], acc1[n4], 0, 0, 0);
    unsigned* sh1u = (unsigned*)sh1[0];
    #pragma unroll
    for (int n4=0;n4<4;++n4){
      int c = 16*(4*w + n4) + r;
      #pragma unroll
      for (int j=0;j<4;++j){
        float v = fmaxf(acc1[n4][j] + b1r[n4], 0.f);
        unsigned mu = f2bf(v);
        unsigned ou = (unsigned)__shfl_xor((int)mu, 1);
        if (!(r & 1)) sh1u[(4*g + j)*132 + (c>>1)] = mu | (ou<<16);
      }
    }
  }
  __syncthreads();
  int cur = 0;

  while (tile < N_TILES){
    int nt = tile + MM_BLOCKS;
    short8 a1n = {0,0,0,0,0,0,0,0};
    if (nt < N_TILES && g == 0)
      a1n = *(const short8*)(x1bf + (size_t)(nt*16 + r)*8);

    // ---- stage 2: yz(tile) = h1 @ W2, from sh1[cur]
    f32x4 acc[4];
    #pragma unroll
    for (int n4=0;n4<4;++n4) acc[n4] = (f32x4){0.f,0.f,0.f,0.f};
    #pragma unroll
    for (int s=0;s<8;++s){
      short8 af = *(const short8*)(sh1[cur] + r*264 + s*32 + 8*g);
      #pragma unroll
      for (int n4=0;n4<4;++n4)
        acc[n4] = __builtin_amdgcn_mfma_f32_16x16x32_bf16(af, B2[s][n4], acc[n4], 0, 0, 0);
    }

    // ---- stage 1 for NEXT tile -> sh1[cur^1] (independent of stage 2)
    if (nt < N_TILES){
      f32x4 acc1[4];
      #pragma unroll
      for (int n4=0;n4<4;++n4) acc1[n4] = (f32x4){0.f,0.f,0.f,0.f};
      #pragma unroll
      for (int n4=0;n4<4;++n4)
        acc1[n4] = __builtin_amdgcn_mfma_f32_16x16x32_bf16(a1n, W1B[n4], acc1[n4], 0, 0, 0);
      unsigned* sh1u = (unsigned*)sh1[cur^1];
      #pragma unroll
      for (int n4=0;n4<4;++n4){
        int c = 16*(4*w + n4) + r;
        #pragma unroll
        for (int j=0;j<4;++j){
          float v = fmaxf(acc1[n4][j] + b1r[n4], 0.f);
          unsigned mu = f2bf(v);
          unsigned ou = (unsigned)__shfl_xor((int)mu, 1);
          if (!(r & 1)) sh1u[(4*g + j)*132 + (c>>1)] = mu | (ou<<16);
        }
      }
    }

    // ---- epilogue: fp8 pack into wave-private LDS slice (no barrier needed)
    #pragma unroll
    for (int n4=0;n4<4;++n4){
      #pragma unroll
      for (int j=0;j<4;++j){
        float v0 = acc[n4][j];
        float v1 = __shfl_xor(v0, 1);
        unsigned p16 = pk_fp8(v0, v1);               // cols (r, r+1), even r lanes
        unsigned hi  = (unsigned)__shfl_xor((int)p16, 2);
        if (!(r & 3))
          Sl[w*256 + (4*g + j)*16 + 4*n4 + (r>>2)] = (p16 & 0xffffu) | (hi<<16);
      }
    }
    // stream own slice out: 16 rows x 64 cols fp8 per wave, coalesced
    {
      const uint4* sl4 = (const uint4*)(Sl + w*256);
      uint4 v = sl4[lane];
      int row = lane>>2, u4 = lane&3;
      size_t rowg = (size_t)tile*16 + row;
      if (w < 2) *(uint4*)(ybuf + rowg*128 + w*64     + u4*16) = v;
      else       *(uint4*)(zbuf + rowg*128 + (w-2)*64 + u4*16) = v;
    }
    __syncthreads();   // sh1[cur^1] visible; sh1[cur] reads drained
    cur ^= 1;
    tile = nt;
  }
}

// ---- gather-aggregate + relu + mean pool -----------------------------------
// One node per wave (uniform off/deg); quarter-wave per edge: 4 edges/round,
// 512B per load instruction, rounds independent -> deep MLP. Clamp+zero
// predication keeps full-width loads on the degree tail (decode(0)=0 exact).
__global__ __launch_bounds__(256) void k_agg2(
    const unsigned char* __restrict__ ybuf, const unsigned char* __restrict__ zbuf,
    const int* __restrict__ csr, const int* __restrict__ offs, const int* __restrict__ cnt,
    const float* __restrict__ b2, float* __restrict__ partials){
  __shared__ float red[128];
  int tid = threadIdx.x;
  if (tid < 128) red[tid] = 0.f;
  __syncthreads();
  int lane = tid & 63, qt = lane>>4, i = lane&15;
  int wave = blockIdx.x*4 + (tid>>6);
  const int nwaves = NB_AGG*4;
  const uint2* y64 = (const uint2*)ybuf;
  const uint2* z64 = (const uint2*)zbuf;
  float bb[8];
  #pragma unroll
  for (int j=0;j<8;++j) bb[j] = b2[8*i + j];
  float pool[8];
  #pragma unroll
  for (int j=0;j<8;++j) pool[j] = 0.f;

  for (int node = wave; node < N_NODES; node += nwaves){
    int off = offs[node], deg = cnt[node];
    uint2 uz = z64[(size_t)node*16 + i];        // independent, issued early
    float acc[8];
    #pragma unroll
    for (int j=0;j<8;++j) acc[j] = 0.f;
    for (int e = 0; e < deg; e += 4){
      int k = e + qt;
      int src = csr[off + min(k, deg-1)];
      uint2 u = y64[(size_t)src*16 + i];
      if (k >= deg){ u.x = 0u; u.y = 0u; }
      acc[0] += DEC_FP8(u.x,0); acc[1] += DEC_FP8(u.x,1);
      acc[2] += DEC_FP8(u.x,2); acc[3] += DEC_FP8(u.x,3);
      acc[4] += DEC_FP8(u.y,0); acc[5] += DEC_FP8(u.y,1);
      acc[6] += DEC_FP8(u.y,2); acc[7] += DEC_FP8(u.y,3);
    }
    #pragma unroll
    for (int j=0;j<8;++j){
      acc[j] += __shfl_xor(acc[j], 16);
      acc[j] += __shfl_xor(acc[j], 32);
    }
    float inv = 1.0f / (float)max(deg,1);
    if (qt == 0){
      pool[0] += fmaxf(acc[0]*inv + DEC_FP8(uz.x,0) + bb[0], 0.f);
      pool[1] += fmaxf(acc[1]*inv + DEC_FP8(uz.x,1) + bb[1], 0.f);
      pool[2] += fmaxf(acc[2]*inv + DEC_FP8(uz.x,2) + bb[2], 0.f);
      pool[3] += fmaxf(acc[3]*inv + DEC_FP8(uz.x,3) + bb[3], 0.f);
      pool[4] += fmaxf(acc[4]*inv + DEC_FP8(uz.y,0) + bb[4], 0.f);
      pool[5] += fmaxf(acc[5]*inv + DEC_FP8(uz.y,1) + bb[5], 0.f);
      pool[6] += fmaxf(acc[6]*inv + DEC_FP8(uz.y,2) + bb[6], 0.f);
      pool[7] += fmaxf(acc[7]*inv + DEC_FP8(uz.y,3) + bb[7], 0.f);
    }
  }
  if (qt == 0){
    #pragma unroll
    for (int j=0;j<8;++j) atomicAdd(&red[8*i + j], pool[j]);
  }
  __syncthreads();
  if (tid < 128) partials[(size_t)blockIdx.x*128 + tid] = red[tid];
}

// ---- reduce partials -> gsum ----------------------------------------------
__global__ void k_red(const float* __restrict__ partials, float* __restrict__ gsum){
  int t = threadIdx.x;  // 128
  float s = 0.f;
  for (int b = blockIdx.x; b < NB_AGG; b += 64) s += partials[(size_t)b*128 + t];
  atomicAdd(&gsum[t], s);
}

// ---- decoder + softmax + argmax -------------------------------------------
__global__ void k_dec(const float* __restrict__ gsum, const float* __restrict__ Wd,
                      const float* __restrict__ bd, float* __restrict__ out, int out_size){
  int lane = threadIdx.x;  // 64
  float l = -1e30f;
  if (lane < 10){
    float s = bd[lane];
    for (int k=0;k<128;++k) s += (gsum[k]*(1.0f/N_NODES)) * Wd[k*10 + lane];
    l = s;
  }
  float m = l;
  #pragma unroll
  for (int d=1; d<16; d<<=1) m = fmaxf(m, __shfl_xor(m, d));
  float e = (lane<10)? expf(l - m) : 0.f;
  float sum = e;
  #pragma unroll
  for (int d=1; d<16; d<<=1) sum += __shfl_xor(sum, d);
  float p = (lane<10)? e/sum : 0.f;
  if (lane < 10) out[lane] = p;
  float v = p; int idx = (lane<10)? lane : 1000;
  #pragma unroll
  for (int d=1; d<16; d<<=1){
    float ov = __shfl_xor(v, d); int oi = __shfl_xor(idx, d);
    if (ov > v || (ov == v && oi < idx)){ v = ov; idx = oi; }
  }
  if (lane == 0 && out_size > 10) out[10] = (float)idx;
}

// ---- launch ----------------------------------------------------------------
extern "C" void kernel_launch(void* const* d_in, const int* in_sizes, int n_in,
                              void* d_out, int out_size, void* d_ws, size_t ws_size,
                              hipStream_t stream){
  const float* pos = (const float*)d_in[0];
  const int*   face= (const int*)  d_in[1];
  const float* W1l = (const float*)d_in[2];
  const float* W1r = (const float*)d_in[3];
  const float* b1  = (const float*)d_in[4];
  const float* W2l = (const float*)d_in[5];
  const float* W2r = (const float*)d_in[6];
  const float* b2  = (const float*)d_in[7];
  const float* Wd  = (const float*)d_in[8];
  const float* bd  = (const float*)d_in[9];

  char* ws = (char*)d_ws;
  size_t o = 0;
  auto alloc = [&](size_t bytes){ size_t rr = o; o += (bytes + 1023) & ~(size_t)1023; return rr; };
  int*   bfill    = (int*)  (ws + alloc(NBUCKETS*4));            // zeroed
  float* gsum     = (float*)(ws + alloc(512));                   // zeroed
  size_t zero_len = o;
  int*   bbase    = (int*)  (ws + alloc(NBUCKETS*4));
  int*   offs     = (int*)  (ws + alloc((size_t)N_NODES*4));
  int*   cnt      = (int*)  (ws + alloc((size_t)N_NODES*4));
  int*   csr      = (int*)  (ws + alloc((size_t)N_EDGES*4));
  unsigned short* bprep = (unsigned short*)(ws + alloc(131072));
  unsigned short* w1p   = (unsigned short*)(ws + alloc(16384));
  unsigned short* x1bf  = (unsigned short*)(ws + alloc((size_t)N_NODES*8*2));
  unsigned char*  ybuf  = (unsigned char*)(ws + alloc((size_t)N_NODES*128));
  unsigned char*  zbuf  = (unsigned char*)(ws + alloc((size_t)N_NODES*128));
  int2*  pairs    = (int2*) (ws + alloc((size_t)NBUCKETS*CAP_BUCKET*8));
  float* partials = (float*)(ws + alloc((size_t)NB_AGG*128*4));

  hipMemsetAsync(ws, 0, zero_len, stream);

  k_bprep<<<256, 256, 0, stream>>>(W2l, W2r, bprep);
  k_w1prep<<<32, 256, 0, stream>>>(W1l, W1r, w1p);
  k_passA<<<NBUCKETS, 256, 0, stream>>>(face, bfill, pairs);
  k_bscan<<<1, 64, 0, stream>>>(bfill, bbase);
  k_passB<<<NBUCKETS, 512, 0, stream>>>(pairs, bfill, bbase, offs, cnt, csr);
  k_x1<<<(N_NODES+255)/256, 256, 0, stream>>>(pos, csr, offs, cnt, x1bf);
  k_mm<<<MM_BLOCKS, 256, 0, stream>>>(x1bf, w1p, b1, bprep, ybuf, zbuf);
  k_agg2<<<NB_AGG, 256, 0, stream>>>(ybuf, zbuf, csr, offs, cnt, b2, partials);
  k_red<<<64, 128, 0, stream>>>(partials, gsum);
  k_dec<<<1, 64, 0, stream>>>(gsum, Wd, bd, (float*)d_out, out_size);
}

// Round 13
// 234.931 us; speedup vs baseline: 1.3613x; 1.1497x over previous
//
#include <hip/hip_runtime.h>
#include <cstdint>
#include <cstddef>

#define N_NODES 200000
#define N_FACES 400000
#define N_EDGES (3*N_FACES)
#define NBUCKETS 196           // ceil(200000/1024), 1024 node-ids per bucket
#define CAP_BUCKET 8192        // mean 6144, sigma~101 -> +20 sigma margin
#define FACES_PER_BLK 2048
#define MM_BLOCKS 512          // 2 blocks/CU exactly; 12500 row-tiles of 16
#define N_TILES 12500
#define NB_AGG 2048            // agg2 blocks

typedef __attribute__((ext_vector_type(8))) short short8;
typedef __attribute__((ext_vector_type(4))) float f32x4;

__device__ __forceinline__ unsigned short f2bf(float f){
  unsigned u = __float_as_uint(f);
  u = u + 0x7fffu + ((u>>16)&1u);   // RNE
  return (unsigned short)(u>>16);
}

// ---- fp8 e4m3fn helpers ----------------------------------------------------
__device__ __forceinline__ unsigned f2fp8(float f){   // RNE encode (fallback)
  unsigned sgn = (__float_as_uint(f) >> 24) & 0x80u;
  float a = fabsf(f);
  a = fminf(a, 448.f);
  unsigned out;
  if (a < 0.015625f){
    out = (unsigned)__float2int_rn(a * 512.f);        // subnormal, 0..8
  } else {
    unsigned m = __float_as_uint(a);
    m = m + 0xFFFFFu + ((m >> 20) & 1u);              // RNE at 3 mantissa bits
    int e = (int)(m >> 23) - 127;                     // -6..8
    out = ((unsigned)(e + 7) << 3) | ((m >> 20) & 7u);
  }
  return out | sgn;
}
__device__ __forceinline__ float fp8tof(unsigned b){  // exact decode (incl subnormals)
  unsigned t = ((b & 0x80u) << 24) | ((b & 0x7fu) << 20);
  return __uint_as_float(t) * 0x1p120f;
}
#if __has_builtin(__builtin_amdgcn_cvt_f32_fp8)
#define DEC_FP8(u, i) __builtin_amdgcn_cvt_f32_fp8((int)(u), (i))
#else
#define DEC_FP8(u, i) fp8tof(((u) >> ((i)*8)) & 0xffu)
#endif
__device__ __forceinline__ unsigned pk_fp8(float a, float b){  // 2 floats -> 2 fp8 bytes
#if __has_builtin(__builtin_amdgcn_cvt_pk_fp8_f32)
  return (unsigned)__builtin_amdgcn_cvt_pk_fp8_f32(a, b, 0, false) & 0xffffu;
#else
  return f2fp8(a) | (f2fp8(b) << 8);
#endif
}

// ---- CSR build, pass A: bin (src,dst) pairs by dst>>10 ---------------------
__global__ __launch_bounds__(256) void k_passA(const int* __restrict__ face,
                                               int* __restrict__ bfill,
                                               int2* __restrict__ pairs){
  __shared__ int hist[NBUCKETS], basel[NBUCKETS], rank[NBUCKETS];
  int tid = threadIdx.x;
  if (tid < NBUCKETS) hist[tid] = 0;
  __syncthreads();
  int f0 = blockIdx.x * FACES_PER_BLK + tid;
  int v0[8], v1[8], v2[8];
  #pragma unroll
  for (int k=0;k<8;++k){
    int f = f0 + k*256;
    if (f < N_FACES){
      v0[k] = face[f]; v1[k] = face[f + N_FACES]; v2[k] = face[f + 2*N_FACES];
    } else { v0[k] = 0; v1[k] = 0; v2[k] = 0; }
  }
  #pragma unroll
  for (int k=0;k<8;++k){
    if (v0[k] != v1[k]) atomicAdd(&hist[v1[k]>>10], 1);
    if (v1[k] != v2[k]) atomicAdd(&hist[v2[k]>>10], 1);
    if (v0[k] != v2[k]) atomicAdd(&hist[v2[k]>>10], 1);
  }
  __syncthreads();
  if (tid < NBUCKETS){
    basel[tid] = atomicAdd(&bfill[tid], hist[tid]);
    rank[tid] = 0;
  }
  __syncthreads();
  #pragma unroll
  for (int k=0;k<8;++k){
    if (v0[k] != v1[k]){
      int b = v1[k]>>10;
      int p = basel[b] + atomicAdd(&rank[b],1);
      if (p < CAP_BUCKET) pairs[(size_t)b*CAP_BUCKET + p] = make_int2(v0[k], v1[k]);
    }
    if (v1[k] != v2[k]){
      int b = v2[k]>>10;
      int p = basel[b] + atomicAdd(&rank[b],1);
      if (p < CAP_BUCKET) pairs[(size_t)b*CAP_BUCKET + p] = make_int2(v1[k], v2[k]);
    }
    if (v0[k] != v2[k]){
      int b = v2[k]>>10;
      int p = basel[b] + atomicAdd(&rank[b],1);
      if (p < CAP_BUCKET) pairs[(size_t)b*CAP_BUCKET + p] = make_int2(v0[k], v2[k]);
    }
  }
}

// ---- exclusive scan of the 196 bucket fills (one wave) ---------------------
__global__ void k_bscan(const int* __restrict__ bfill, int* __restrict__ bbase){
  int l = threadIdx.x;  // 64
  int v[4]; int s = 0;
  #pragma unroll
  for (int k=0;k<4;++k){ int i = l*4+k; v[k] = (i < NBUCKETS)? min(bfill[i], CAP_BUCKET) : 0; s += v[k]; }
  int inc = s;
  #pragma unroll
  for (int d=1; d<64; d<<=1){ int t = __shfl_up(inc, d); if (l >= d) inc += t; }
  int pre = inc - s;
  #pragma unroll
  for (int k=0;k<4;++k){ int i = l*4+k; if (i < NBUCKETS) bbase[i] = pre; pre += v[k]; }
}

// ---- CSR build, pass B: per-bucket LDS counting sort -----------------------
__global__ __launch_bounds__(512) void k_passB(const int2* __restrict__ pairs,
                                               const int* __restrict__ bfill,
                                               const int* __restrict__ bbase,
                                               int* __restrict__ offs, int* __restrict__ cnt,
                                               int* __restrict__ csr){
  __shared__ int lcnt[1024], lfill[1024], sc[512];
  __shared__ int lcsr[CAP_BUCKET];
  int b = blockIdx.x, tid = threadIdx.x;
  int nb = min(bfill[b], CAP_BUCKET);
  int base = bbase[b];
  const int2* bp = pairs + (size_t)b*CAP_BUCKET;
  lcnt[tid] = 0; lcnt[tid+512] = 0;
  __syncthreads();
  for (int i = tid; i < nb; i += 512){
    int2 e = bp[i];
    atomicAdd(&lcnt[e.y & 1023], 1);
  }
  __syncthreads();
  int c0 = lcnt[2*tid], c1 = lcnt[2*tid+1];
  int s = c0 + c1;
  sc[tid] = s; __syncthreads();
  for (int d=1; d<512; d<<=1){
    int v = (tid>=d)? sc[tid-d] : 0; __syncthreads();
    sc[tid] += v; __syncthreads();
  }
  int excl = sc[tid] - s;
  lfill[2*tid] = excl; lfill[2*tid+1] = excl + c0;
  int g0 = b*1024 + 2*tid, g1 = g0 + 1;
  if (g0 < N_NODES){ offs[g0] = base + excl;      cnt[g0] = c0; }
  if (g1 < N_NODES){ offs[g1] = base + excl + c0; cnt[g1] = c1; }
  __syncthreads();
  for (int i = tid; i < nb; i += 512){
    int2 e = bp[i];
    int p = atomicAdd(&lfill[e.y & 1023], 1);
    lcsr[p] = e.x;
  }
  __syncthreads();
  for (int i = tid; i < nb; i += 512){
    csr[base + i] = lcsr[i];
  }
}

// ---- stage-2 B pre-pack: [W2l|W2r] (256K x 256N) into MFMA fragment order --
// bp[((s*16+n)*64+l)*8+j] = Bstack[32s+8*(l>>4)+j][16n+(l&15)]
__global__ void k_bprep(const float* __restrict__ W2l, const float* __restrict__ W2r,
                        unsigned short* __restrict__ bp){
  int idx = blockIdx.x*256 + threadIdx.x;   // 65536 total
  int j = idx & 7, l = (idx>>3)&63, n = (idx>>9)&15, s = idx>>13;
  int k = 32*s + 8*(l>>4) + j;
  int c = 16*n + (l&15);
  float v = (c < 128)? W2l[k*128 + c] : W2r[k*128 + (c-128)];
  bp[idx] = f2bf(v);
}

// ---- stage-1 B pre-pack: [W1l;W1r] (6 x 256) K-padded to 32, frag order ----
__global__ void k_w1prep(const float* __restrict__ W1l, const float* __restrict__ W1r,
                         unsigned short* __restrict__ w1p){
  int idx = blockIdx.x*256 + threadIdx.x;   // 8192 total
  int j = idx & 7, l = (idx>>3)&63, n = idx>>9;   // n in [0,16)
  int k = 8*(l>>4) + j;
  int c = 16*n + (l&15);
  float v = 0.f;
  if (k < 3) v = W1l[k*256 + c];
  else if (k < 6) v = W1r[(k-3)*256 + c];
  w1p[idx] = f2bf(v);
}

// ---- x1: per node, mean of neighbor pos + own pos, packed bf16 [8] --------
__global__ void k_x1(const float* __restrict__ pos, const int* __restrict__ csr,
                     const int* __restrict__ offs, const int* __restrict__ cnt,
                     unsigned short* __restrict__ x1bf){
  int i = blockIdx.x*256 + threadIdx.x;
  if (i >= N_NODES) return;
  int off = offs[i], deg = cnt[i];
  float s0=0.f, s1=0.f, s2=0.f;
  int e = 0;
  for (; e+2 <= deg; e += 2){
    int a = csr[off+e], b = csr[off+e+1];
    const float* pa = pos + 3*a; const float* pb = pos + 3*b;
    s0 += pa[0] + pb[0]; s1 += pa[1] + pb[1]; s2 += pa[2] + pb[2];
  }
  if (e < deg){
    const float* pa = pos + 3*csr[off+e];
    s0 += pa[0]; s1 += pa[1]; s2 += pa[2];
  }
  float inv = 1.0f / (float)max(deg,1);
  float p0 = pos[3*i], p1 = pos[3*i+1], p2 = pos[3*i+2];
  uint4 pk;
  pk.x = (unsigned)f2bf(s0*inv) | ((unsigned)f2bf(s1*inv)<<16);
  pk.y = (unsigned)f2bf(s2*inv) | ((unsigned)f2bf(p0)<<16);
  pk.z = (unsigned)f2bf(p1)     | ((unsigned)f2bf(p2)<<16);
  pk.w = 0;
  *(uint4*)(x1bf + (size_t)i*8) = pk;
}

// ---- fused double GEMM, 1-barrier pipeline, shuffle-free pack/store --------
// stage2 consumes sh1[cur] while stage1 produces sh1[cur^1] for the NEXT tile.
// sh1 pack: direct ds_write_b16 per lane (2-way bank alias, free).
// yz out: direct per-lane fp8 byte stores (L2 merges 16B/row segments).
// x1 loads prefetched 2 tiles deep.
__global__ __launch_bounds__(256,2) void k_mm(
    const unsigned short* __restrict__ x1bf,
    const unsigned short* __restrict__ w1p,
    const float* __restrict__ b1,
    const unsigned short* __restrict__ bp,
    unsigned char* __restrict__ ybuf,
    unsigned char* __restrict__ zbuf){
  __shared__ unsigned short sh1[2][16*264];   // 2 x 8.25 KB, 528B row stride
  int tid = threadIdx.x;
  int w = tid>>6, lane = tid&63, r = lane&15, g = lane>>4;

  // stage-2 B frags (cols 64w..64w+64), held whole kernel
  short8 B2[8][4];
  #pragma unroll
  for (int s=0;s<8;++s)
    #pragma unroll
    for (int n4=0;n4<4;++n4)
      B2[s][n4] = *(const short8*)(bp + ((size_t)((s*16 + 4*w + n4)*64 + lane))*8);
  // stage-1 B frags + bias
  short8 W1B[4];
  float b1r[4];
  #pragma unroll
  for (int n4=0;n4<4;++n4){
    W1B[n4] = *(const short8*)(w1p + ((size_t)((4*w + n4)*64 + lane))*8);
    b1r[n4] = b1[16*(4*w + n4) + r];
  }

  const short8 zero8 = {0,0,0,0,0,0,0,0};
  int tile = blockIdx.x;

  // x1 pipeline: a1_nx for tile+MM_BLOCKS, a1_nx2 for tile+2*MM_BLOCKS
  short8 a1_cur = zero8, a1_nx = zero8;
  if (g == 0){
    a1_cur = *(const short8*)(x1bf + (size_t)(tile*16 + r)*8);
    int n1 = tile + MM_BLOCKS;
    if (n1 < N_TILES) a1_nx = *(const short8*)(x1bf + (size_t)(n1*16 + r)*8);
  }

  // ---- prologue: stage1 for first tile -> sh1[0]
  {
    f32x4 acc1[4];
    #pragma unroll
    for (int n4=0;n4<4;++n4) acc1[n4] = (f32x4){0.f,0.f,0.f,0.f};
    #pragma unroll
    for (int n4=0;n4<4;++n4)
      acc1[n4] = __builtin_amdgcn_mfma_f32_16x16x32_bf16(a1_cur, W1B[n4], acc1[n4], 0, 0, 0);
    #pragma unroll
    for (int n4=0;n4<4;++n4){
      int c = 16*(4*w + n4) + r;
      #pragma unroll
      for (int j=0;j<4;++j){
        float v = fmaxf(acc1[n4][j] + b1r[n4], 0.f);
        sh1[0][(4*g + j)*264 + c] = f2bf(v);
      }
    }
  }
  __syncthreads();
  int cur = 0;

  while (tile < N_TILES){
    int nt = tile + MM_BLOCKS;
    int nt2 = tile + 2*MM_BLOCKS;
    short8 a1_nx2 = zero8;
    if (nt2 < N_TILES && g == 0)
      a1_nx2 = *(const short8*)(x1bf + (size_t)(nt2*16 + r)*8);   // 2-deep prefetch

    // ---- stage 2: yz(tile) = h1 @ W2, from sh1[cur]
    f32x4 acc[4];
    #pragma unroll
    for (int n4=0;n4<4;++n4) acc[n4] = (f32x4){0.f,0.f,0.f,0.f};
    #pragma unroll
    for (int s=0;s<8;++s){
      short8 af = *(const short8*)(sh1[cur] + r*264 + s*32 + 8*g);
      #pragma unroll
      for (int n4=0;n4<4;++n4)
        acc[n4] = __builtin_amdgcn_mfma_f32_16x16x32_bf16(af, B2[s][n4], acc[n4], 0, 0, 0);
    }

    // ---- stage 1 for NEXT tile -> sh1[cur^1], shuffle-free b16 writes
    if (nt < N_TILES){
      f32x4 acc1[4];
      #pragma unroll
      for (int n4=0;n4<4;++n4) acc1[n4] = (f32x4){0.f,0.f,0.f,0.f};
      #pragma unroll
      for (int n4=0;n4<4;++n4)
        acc1[n4] = __builtin_amdgcn_mfma_f32_16x16x32_bf16(a1_nx, W1B[n4], acc1[n4], 0, 0, 0);
      #pragma unroll
      for (int n4=0;n4<4;++n4){
        int c = 16*(4*w + n4) + r;
        #pragma unroll
        for (int j=0;j<4;++j){
          float v = fmaxf(acc1[n4][j] + b1r[n4], 0.f);
          sh1[cur^1][(4*g + j)*264 + c] = f2bf(v);
        }
      }
    }

    // ---- epilogue: direct fp8 byte stores (no LDS, no shuffles)
    {
      unsigned char* obase = (w < 2)? ybuf : zbuf;
      int cbase = 16*(4*w) - ((w < 2)? 0 : 128);
      #pragma unroll
      for (int n4=0;n4<4;++n4){
        int col = cbase + 16*n4 + r;
        #pragma unroll
        for (int j=0;j<4;++j){
          unsigned b8 = pk_fp8(acc[n4][j], 0.f) & 0xffu;
          size_t rowg = (size_t)tile*16 + 4*g + j;
          obase[rowg*128 + col] = (unsigned char)b8;
        }
      }
    }
    __syncthreads();   // sh1[cur^1] visible; sh1[cur] reads drained
    a1_cur = a1_nx; a1_nx = a1_nx2;
    cur ^= 1;
    tile = nt;
  }
}

// ---- gather-aggregate + relu + mean pool -----------------------------------
// One node per wave (uniform off/deg); quarter-wave per edge: 4 edges/round,
// 512B per load instruction, rounds independent -> deep MLP. Clamp+zero
// predication keeps full-width loads on the degree tail (decode(0)=0 exact).
__global__ __launch_bounds__(256) void k_agg2(
    const unsigned char* __restrict__ ybuf, const unsigned char* __restrict__ zbuf,
    const int* __restrict__ csr, const int* __restrict__ offs, const int* __restrict__ cnt,
    const float* __restrict__ b2, float* __restrict__ partials){
  __shared__ float red[128];
  int tid = threadIdx.x;
  if (tid < 128) red[tid] = 0.f;
  __syncthreads();
  int lane = tid & 63, qt = lane>>4, i = lane&15;
  int wave = blockIdx.x*4 + (tid>>6);
  const int nwaves = NB_AGG*4;
  const uint2* y64 = (const uint2*)ybuf;
  const uint2* z64 = (const uint2*)zbuf;
  float bb[8];
  #pragma unroll
  for (int j=0;j<8;++j) bb[j] = b2[8*i + j];
  float pool[8];
  #pragma unroll
  for (int j=0;j<8;++j) pool[j] = 0.f;

  for (int node = wave; node < N_NODES; node += nwaves){
    int off = offs[node], deg = cnt[node];
    uint2 uz = z64[(size_t)node*16 + i];        // independent, issued early
    float acc[8];
    #pragma unroll
    for (int j=0;j<8;++j) acc[j] = 0.f;
    for (int e = 0; e < deg; e += 4){
      int k = e + qt;
      int src = csr[off + min(k, deg-1)];
      uint2 u = y64[(size_t)src*16 + i];
      if (k >= deg){ u.x = 0u; u.y = 0u; }
      acc[0] += DEC_FP8(u.x,0); acc[1] += DEC_FP8(u.x,1);
      acc[2] += DEC_FP8(u.x,2); acc[3] += DEC_FP8(u.x,3);
      acc[4] += DEC_FP8(u.y,0); acc[5] += DEC_FP8(u.y,1);
      acc[6] += DEC_FP8(u.y,2); acc[7] += DEC_FP8(u.y,3);
    }
    #pragma unroll
    for (int j=0;j<8;++j){
      acc[j] += __shfl_xor(acc[j], 16);
      acc[j] += __shfl_xor(acc[j], 32);
    }
    float inv = 1.0f / (float)max(deg,1);
    if (qt == 0){
      pool[0] += fmaxf(acc[0]*inv + DEC_FP8(uz.x,0) + bb[0], 0.f);
      pool[1] += fmaxf(acc[1]*inv + DEC_FP8(uz.x,1) + bb[1], 0.f);
      pool[2] += fmaxf(acc[2]*inv + DEC_FP8(uz.x,2) + bb[2], 0.f);
      pool[3] += fmaxf(acc[3]*inv + DEC_FP8(uz.x,3) + bb[3], 0.f);
      pool[4] += fmaxf(acc[4]*inv + DEC_FP8(uz.y,0) + bb[4], 0.f);
      pool[5] += fmaxf(acc[5]*inv + DEC_FP8(uz.y,1) + bb[5], 0.f);
      pool[6] += fmaxf(acc[6]*inv + DEC_FP8(uz.y,2) + bb[6], 0.f);
      pool[7] += fmaxf(acc[7]*inv + DEC_FP8(uz.y,3) + bb[7], 0.f);
    }
  }
  if (qt == 0){
    #pragma unroll
    for (int j=0;j<8;++j) atomicAdd(&red[8*i + j], pool[j]);
  }
  __syncthreads();
  if (tid < 128) partials[(size_t)blockIdx.x*128 + tid] = red[tid];
}

// ---- reduce partials -> gsum ----------------------------------------------
__global__ void k_red(const float* __restrict__ partials, float* __restrict__ gsum){
  int t = threadIdx.x;  // 128
  float s = 0.f;
  for (int b = blockIdx.x; b < NB_AGG; b += 64) s += partials[(size_t)b*128 + t];
  atomicAdd(&gsum[t], s);
}

// ---- decoder + softmax + argmax -------------------------------------------
__global__ void k_dec(const float* __restrict__ gsum, const float* __restrict__ Wd,
                      const float* __restrict__ bd, float* __restrict__ out, int out_size){
  int lane = threadIdx.x;  // 64
  float l = -1e30f;
  if (lane < 10){
    float s = bd[lane];
    for (int k=0;k<128;++k) s += (gsum[k]*(1.0f/N_NODES)) * Wd[k*10 + lane];
    l = s;
  }
  float m = l;
  #pragma unroll
  for (int d=1; d<16; d<<=1) m = fmaxf(m, __shfl_xor(m, d));
  float e = (lane<10)? expf(l - m) : 0.f;
  float sum = e;
  #pragma unroll
  for (int d=1; d<16; d<<=1) sum += __shfl_xor(sum, d);
  float p = (lane<10)? e/sum : 0.f;
  if (lane < 10) out[lane] = p;
  float v = p; int idx = (lane<10)? lane : 1000;
  #pragma unroll
  for (int d=1; d<16; d<<=1){
    float ov = __shfl_xor(v, d); int oi = __shfl_xor(idx, d);
    if (ov > v || (ov == v && oi < idx)){ v = ov; idx = oi; }
  }
  if (lane == 0 && out_size > 10) out[10] = (float)idx;
}

// ---- launch ----------------------------------------------------------------
extern "C" void kernel_launch(void* const* d_in, const int* in_sizes, int n_in,
                              void* d_out, int out_size, void* d_ws, size_t ws_size,
                              hipStream_t stream){
  const float* pos = (const float*)d_in[0];
  const int*   face= (const int*)  d_in[1];
  const float* W1l = (const float*)d_in[2];
  const float* W1r = (const float*)d_in[3];
  const float* b1  = (const float*)d_in[4];
  const float* W2l = (const float*)d_in[5];
  const float* W2r = (const float*)d_in[6];
  const float* b2  = (const float*)d_in[7];
  const float* Wd  = (const float*)d_in[8];
  const float* bd  = (const float*)d_in[9];

  char* ws = (char*)d_ws;
  size_t o = 0;
  auto alloc = [&](size_t bytes){ size_t rr = o; o += (bytes + 1023) & ~(size_t)1023; return rr; };
  int*   bfill    = (int*)  (ws + alloc(NBUCKETS*4));            // zeroed
  float* gsum     = (float*)(ws + alloc(512));                   // zeroed
  size_t zero_len = o;
  int*   bbase    = (int*)  (ws + alloc(NBUCKETS*4));
  int*   offs     = (int*)  (ws + alloc((size_t)N_NODES*4));
  int*   cnt      = (int*)  (ws + alloc((size_t)N_NODES*4));
  int*   csr      = (int*)  (ws + alloc((size_t)N_EDGES*4));
  unsigned short* bprep = (unsigned short*)(ws + alloc(131072));
  unsigned short* w1p   = (unsigned short*)(ws + alloc(16384));
  unsigned short* x1bf  = (unsigned short*)(ws + alloc((size_t)N_NODES*8*2));
  unsigned char*  ybuf  = (unsigned char*)(ws + alloc((size_t)N_NODES*128));
  unsigned char*  zbuf  = (unsigned char*)(ws + alloc((size_t)N_NODES*128));
  int2*  pairs    = (int2*) (ws + alloc((size_t)NBUCKETS*CAP_BUCKET*8));
  float* partials = (float*)(ws + alloc((size_t)NB_AGG*128*4));

  hipMemsetAsync(ws, 0, zero_len, stream);

  k_bprep<<<256, 256, 0, stream>>>(W2l, W2r, bprep);
  k_w1prep<<<32, 256, 0, stream>>>(W1l, W1r, w1p);
  k_passA<<<NBUCKETS, 256, 0, stream>>>(face, bfill, pairs);
  k_bscan<<<1, 64, 0, stream>>>(bfill, bbase);
  k_passB<<<NBUCKETS, 512, 0, stream>>>(pairs, bfill, bbase, offs, cnt, csr);
  k_x1<<<(N_NODES+255)/256, 256, 0, stream>>>(pos, csr, offs, cnt, x1bf);
  k_mm<<<MM_BLOCKS, 256, 0, stream>>>(x1bf, w1p, b1, bprep, ybuf, zbuf);
  k_agg2<<<NB_AGG, 256, 0, stream>>>(ybuf, zbuf, csr, offs, cnt, b2, partials);
  k_red<<<64, 128, 0, stream>>>(partials, gsum);
  k_dec<<<1, 64, 0, stream>>>(gsum, Wd, bd, (float*)d_out, out_size);
}

// Round 14
// 216.175 us; speedup vs baseline: 1.4795x; 1.0868x over previous
//
#include <hip/hip_runtime.h>
#include <cstdint>
#include <cstddef>

#define N_NODES 200000
#define N_FACES 400000
#define N_EDGES (3*N_FACES)
#define NBUCKETS 196           // ceil(200000/1024), 1024 node-ids per bucket
#define CAP_BUCKET 8192        // mean 6144, sigma~101 -> +20 sigma margin
#define FACES_PER_BLK 2048
#define MM_BLOCKS 512          // 2 blocks/CU exactly; 12500 row-tiles of 16
#define N_TILES 12500
#define NB_AGG 2048            // agg2 blocks

typedef __attribute__((ext_vector_type(8))) short short8;
typedef __attribute__((ext_vector_type(4))) float f32x4;

__device__ __forceinline__ unsigned short f2bf(float f){
  unsigned u = __float_as_uint(f);
  u = u + 0x7fffu + ((u>>16)&1u);   // RNE
  return (unsigned short)(u>>16);
}

// ---- fp8 e4m3fn helpers ----------------------------------------------------
__device__ __forceinline__ unsigned f2fp8(float f){   // RNE encode (fallback)
  unsigned sgn = (__float_as_uint(f) >> 24) & 0x80u;
  float a = fabsf(f);
  a = fminf(a, 448.f);
  unsigned out;
  if (a < 0.015625f){
    out = (unsigned)__float2int_rn(a * 512.f);        // subnormal, 0..8
  } else {
    unsigned m = __float_as_uint(a);
    m = m + 0xFFFFFu + ((m >> 20) & 1u);              // RNE at 3 mantissa bits
    int e = (int)(m >> 23) - 127;                     // -6..8
    out = ((unsigned)(e + 7) << 3) | ((m >> 20) & 7u);
  }
  return out | sgn;
}
__device__ __forceinline__ float fp8tof(unsigned b){  // exact decode (incl subnormals)
  unsigned t = ((b & 0x80u) << 24) | ((b & 0x7fu) << 20);
  return __uint_as_float(t) * 0x1p120f;
}
#if __has_builtin(__builtin_amdgcn_cvt_f32_fp8)
#define DEC_FP8(u, i) __builtin_amdgcn_cvt_f32_fp8((int)(u), (i))
#else
#define DEC_FP8(u, i) fp8tof(((u) >> ((i)*8)) & 0xffu)
#endif
__device__ __forceinline__ unsigned pk_fp8(float a, float b){  // 2 floats -> 2 fp8 bytes
#if __has_builtin(__builtin_amdgcn_cvt_pk_fp8_f32)
  return (unsigned)__builtin_amdgcn_cvt_pk_fp8_f32(a, b, 0, false) & 0xffffu;
#else
  return f2fp8(a) | (f2fp8(b) << 8);
#endif
}

// ---- CSR build, pass A: bin (src,dst) pairs by dst>>10 ---------------------
__global__ __launch_bounds__(256) void k_passA(const int* __restrict__ face,
                                               int* __restrict__ bfill,
                                               int2* __restrict__ pairs){
  __shared__ int hist[NBUCKETS], basel[NBUCKETS], rank[NBUCKETS];
  int tid = threadIdx.x;
  if (tid < NBUCKETS) hist[tid] = 0;
  __syncthreads();
  int f0 = blockIdx.x * FACES_PER_BLK + tid;
  int v0[8], v1[8], v2[8];
  #pragma unroll
  for (int k=0;k<8;++k){
    int f = f0 + k*256;
    if (f < N_FACES){
      v0[k] = face[f]; v1[k] = face[f + N_FACES]; v2[k] = face[f + 2*N_FACES];
    } else { v0[k] = 0; v1[k] = 0; v2[k] = 0; }
  }
  #pragma unroll
  for (int k=0;k<8;++k){
    if (v0[k] != v1[k]) atomicAdd(&hist[v1[k]>>10], 1);
    if (v1[k] != v2[k]) atomicAdd(&hist[v2[k]>>10], 1);
    if (v0[k] != v2[k]) atomicAdd(&hist[v2[k]>>10], 1);
  }
  __syncthreads();
  if (tid < NBUCKETS){
    basel[tid] = atomicAdd(&bfill[tid], hist[tid]);
    rank[tid] = 0;
  }
  __syncthreads();
  #pragma unroll
  for (int k=0;k<8;++k){
    if (v0[k] != v1[k]){
      int b = v1[k]>>10;
      int p = basel[b] + atomicAdd(&rank[b],1);
      if (p < CAP_BUCKET) pairs[(size_t)b*CAP_BUCKET + p] = make_int2(v0[k], v1[k]);
    }
    if (v1[k] != v2[k]){
      int b = v2[k]>>10;
      int p = basel[b] + atomicAdd(&rank[b],1);
      if (p < CAP_BUCKET) pairs[(size_t)b*CAP_BUCKET + p] = make_int2(v1[k], v2[k]);
    }
    if (v0[k] != v2[k]){
      int b = v2[k]>>10;
      int p = basel[b] + atomicAdd(&rank[b],1);
      if (p < CAP_BUCKET) pairs[(size_t)b*CAP_BUCKET + p] = make_int2(v0[k], v2[k]);
    }
  }
}

// ---- exclusive scan of the 196 bucket fills (one wave) ---------------------
__global__ void k_bscan(const int* __restrict__ bfill, int* __restrict__ bbase){
  int l = threadIdx.x;  // 64
  int v[4]; int s = 0;
  #pragma unroll
  for (int k=0;k<4;++k){ int i = l*4+k; v[k] = (i < NBUCKETS)? min(bfill[i], CAP_BUCKET) : 0; s += v[k]; }
  int inc = s;
  #pragma unroll
  for (int d=1; d<64; d<<=1){ int t = __shfl_up(inc, d); if (l >= d) inc += t; }
  int pre = inc - s;
  #pragma unroll
  for (int k=0;k<4;++k){ int i = l*4+k; if (i < NBUCKETS) bbase[i] = pre; pre += v[k]; }
}

// ---- CSR build, pass B: per-bucket LDS counting sort -----------------------
__global__ __launch_bounds__(512) void k_passB(const int2* __restrict__ pairs,
                                               const int* __restrict__ bfill,
                                               const int* __restrict__ bbase,
                                               int* __restrict__ offs, int* __restrict__ cnt,
                                               int* __restrict__ csr){
  __shared__ int lcnt[1024], lfill[1024], sc[512];
  __shared__ int lcsr[CAP_BUCKET];
  int b = blockIdx.x, tid = threadIdx.x;
  int nb = min(bfill[b], CAP_BUCKET);
  int base = bbase[b];
  const int2* bp = pairs + (size_t)b*CAP_BUCKET;
  lcnt[tid] = 0; lcnt[tid+512] = 0;
  __syncthreads();
  for (int i = tid; i < nb; i += 512){
    int2 e = bp[i];
    atomicAdd(&lcnt[e.y & 1023], 1);
  }
  __syncthreads();
  int c0 = lcnt[2*tid], c1 = lcnt[2*tid+1];
  int s = c0 + c1;
  sc[tid] = s; __syncthreads();
  for (int d=1; d<512; d<<=1){
    int v = (tid>=d)? sc[tid-d] : 0; __syncthreads();
    sc[tid] += v; __syncthreads();
  }
  int excl = sc[tid] - s;
  lfill[2*tid] = excl; lfill[2*tid+1] = excl + c0;
  int g0 = b*1024 + 2*tid, g1 = g0 + 1;
  if (g0 < N_NODES){ offs[g0] = base + excl;      cnt[g0] = c0; }
  if (g1 < N_NODES){ offs[g1] = base + excl + c0; cnt[g1] = c1; }
  __syncthreads();
  for (int i = tid; i < nb; i += 512){
    int2 e = bp[i];
    int p = atomicAdd(&lfill[e.y & 1023], 1);
    lcsr[p] = e.x;
  }
  __syncthreads();
  for (int i = tid; i < nb; i += 512){
    csr[base + i] = lcsr[i];
  }
}

// ---- stage-2 B pre-pack: [W2l|W2r] (256K x 256N) into MFMA fragment order --
// bp[((s*16+n)*64+l)*8+j] = Bstack[32s+8*(l>>4)+j][16n+(l&15)]
__global__ void k_bprep(const float* __restrict__ W2l, const float* __restrict__ W2r,
                        unsigned short* __restrict__ bp){
  int idx = blockIdx.x*256 + threadIdx.x;   // 65536 total
  int j = idx & 7, l = (idx>>3)&63, n = (idx>>9)&15, s = idx>>13;
  int k = 32*s + 8*(l>>4) + j;
  int c = 16*n + (l&15);
  float v = (c < 128)? W2l[k*128 + c] : W2r[k*128 + (c-128)];
  bp[idx] = f2bf(v);
}

// ---- stage-1 B pre-pack: [W1l;W1r] (6 x 256) K-padded to 32, frag order ----
__global__ void k_w1prep(const float* __restrict__ W1l, const float* __restrict__ W1r,
                         unsigned short* __restrict__ w1p){
  int idx = blockIdx.x*256 + threadIdx.x;   // 8192 total
  int j = idx & 7, l = (idx>>3)&63, n = idx>>9;   // n in [0,16)
  int k = 8*(l>>4) + j;
  int c = 16*n + (l&15);
  float v = 0.f;
  if (k < 3) v = W1l[k*256 + c];
  else if (k < 6) v = W1r[(k-3)*256 + c];
  w1p[idx] = f2bf(v);
}

// ---- x1: per node, mean of neighbor pos + own pos, packed bf16 [8] --------
__global__ void k_x1(const float* __restrict__ pos, const int* __restrict__ csr,
                     const int* __restrict__ offs, const int* __restrict__ cnt,
                     unsigned short* __restrict__ x1bf){
  int i = blockIdx.x*256 + threadIdx.x;
  if (i >= N_NODES) return;
  int off = offs[i], deg = cnt[i];
  float s0=0.f, s1=0.f, s2=0.f;
  int e = 0;
  for (; e+2 <= deg; e += 2){
    int a = csr[off+e], b = csr[off+e+1];
    const float* pa = pos + 3*a; const float* pb = pos + 3*b;
    s0 += pa[0] + pb[0]; s1 += pa[1] + pb[1]; s2 += pa[2] + pb[2];
  }
  if (e < deg){
    const float* pa = pos + 3*csr[off+e];
    s0 += pa[0]; s1 += pa[1]; s2 += pa[2];
  }
  float inv = 1.0f / (float)max(deg,1);
  float p0 = pos[3*i], p1 = pos[3*i+1], p2 = pos[3*i+2];
  uint4 pk;
  pk.x = (unsigned)f2bf(s0*inv) | ((unsigned)f2bf(s1*inv)<<16);
  pk.y = (unsigned)f2bf(s2*inv) | ((unsigned)f2bf(p0)<<16);
  pk.z = (unsigned)f2bf(p1)     | ((unsigned)f2bf(p2)<<16);
  pk.w = 0;
  *(uint4*)(x1bf + (size_t)i*8) = pk;
}

// ---- fused double GEMM, 1-barrier pipeline, shuffle-free pack/store --------
__global__ __launch_bounds__(256,2) void k_mm(
    const unsigned short* __restrict__ x1bf,
    const unsigned short* __restrict__ w1p,
    const float* __restrict__ b1,
    const unsigned short* __restrict__ bp,
    unsigned char* __restrict__ ybuf,
    unsigned char* __restrict__ zbuf){
  __shared__ unsigned short sh1[2][16*264];   // 2 x 8.25 KB, 528B row stride
  int tid = threadIdx.x;
  int w = tid>>6, lane = tid&63, r = lane&15, g = lane>>4;

  short8 B2[8][4];
  #pragma unroll
  for (int s=0;s<8;++s)
    #pragma unroll
    for (int n4=0;n4<4;++n4)
      B2[s][n4] = *(const short8*)(bp + ((size_t)((s*16 + 4*w + n4)*64 + lane))*8);
  short8 W1B[4];
  float b1r[4];
  #pragma unroll
  for (int n4=0;n4<4;++n4){
    W1B[n4] = *(const short8*)(w1p + ((size_t)((4*w + n4)*64 + lane))*8);
    b1r[n4] = b1[16*(4*w + n4) + r];
  }

  const short8 zero8 = {0,0,0,0,0,0,0,0};
  int tile = blockIdx.x;

  short8 a1_cur = zero8, a1_nx = zero8;
  if (g == 0){
    a1_cur = *(const short8*)(x1bf + (size_t)(tile*16 + r)*8);
    int n1 = tile + MM_BLOCKS;
    if (n1 < N_TILES) a1_nx = *(const short8*)(x1bf + (size_t)(n1*16 + r)*8);
  }

  {
    f32x4 acc1[4];
    #pragma unroll
    for (int n4=0;n4<4;++n4) acc1[n4] = (f32x4){0.f,0.f,0.f,0.f};
    #pragma unroll
    for (int n4=0;n4<4;++n4)
      acc1[n4] = __builtin_amdgcn_mfma_f32_16x16x32_bf16(a1_cur, W1B[n4], acc1[n4], 0, 0, 0);
    #pragma unroll
    for (int n4=0;n4<4;++n4){
      int c = 16*(4*w + n4) + r;
      #pragma unroll
      for (int j=0;j<4;++j){
        float v = fmaxf(acc1[n4][j] + b1r[n4], 0.f);
        sh1[0][(4*g + j)*264 + c] = f2bf(v);
      }
    }
  }
  __syncthreads();
  int cur = 0;

  while (tile < N_TILES){
    int nt = tile + MM_BLOCKS;
    int nt2 = tile + 2*MM_BLOCKS;
    short8 a1_nx2 = zero8;
    if (nt2 < N_TILES && g == 0)
      a1_nx2 = *(const short8*)(x1bf + (size_t)(nt2*16 + r)*8);   // 2-deep prefetch

    f32x4 acc[4];
    #pragma unroll
    for (int n4=0;n4<4;++n4) acc[n4] = (f32x4){0.f,0.f,0.f,0.f};
    #pragma unroll
    for (int s=0;s<8;++s){
      short8 af = *(const short8*)(sh1[cur] + r*264 + s*32 + 8*g);
      #pragma unroll
      for (int n4=0;n4<4;++n4)
        acc[n4] = __builtin_amdgcn_mfma_f32_16x16x32_bf16(af, B2[s][n4], acc[n4], 0, 0, 0);
    }

    if (nt < N_TILES){
      f32x4 acc1[4];
      #pragma unroll
      for (int n4=0;n4<4;++n4) acc1[n4] = (f32x4){0.f,0.f,0.f,0.f};
      #pragma unroll
      for (int n4=0;n4<4;++n4)
        acc1[n4] = __builtin_amdgcn_mfma_f32_16x16x32_bf16(a1_nx, W1B[n4], acc1[n4], 0, 0, 0);
      #pragma unroll
      for (int n4=0;n4<4;++n4){
        int c = 16*(4*w + n4) + r;
        #pragma unroll
        for (int j=0;j<4;++j){
          float v = fmaxf(acc1[n4][j] + b1r[n4], 0.f);
          sh1[cur^1][(4*g + j)*264 + c] = f2bf(v);
        }
      }
    }

    {
      unsigned char* obase = (w < 2)? ybuf : zbuf;
      int cbase = 16*(4*w) - ((w < 2)? 0 : 128);
      #pragma unroll
      for (int n4=0;n4<4;++n4){
        int col = cbase + 16*n4 + r;
        #pragma unroll
        for (int j=0;j<4;++j){
          unsigned b8 = pk_fp8(acc[n4][j], 0.f) & 0xffu;
          size_t rowg = (size_t)tile*16 + 4*g + j;
          obase[rowg*128 + col] = (unsigned char)b8;
        }
      }
    }
    __syncthreads();
    a1_cur = a1_nx; a1_nx = a1_nx2;
    cur ^= 1;
    tile = nt;
  }
}

// ---- gather-aggregate + relu + mean pool -----------------------------------
// QUARTER-WAVE PER NODE: each 16-lane quarter owns one node end-to-end
// (own edge loop unrolled x2, own acc, relu+pool). No cross-quarter reduce,
// no clamp waste; 4 independent node streams per wave keep ~8 loads in flight.
__global__ __launch_bounds__(256) void k_agg2(
    const unsigned char* __restrict__ ybuf, const unsigned char* __restrict__ zbuf,
    const int* __restrict__ csr, const int* __restrict__ offs, const int* __restrict__ cnt,
    const float* __restrict__ b2, float* __restrict__ partials){
  __shared__ float red[128];
  int tid = threadIdx.x;
  if (tid < 128) red[tid] = 0.f;
  __syncthreads();
  int i = tid & 15;                       // lane within quarter
  int qg = blockIdx.x*16 + (tid>>4);      // global quarter id
  const int nq = NB_AGG*16;
  const uint2* y64 = (const uint2*)ybuf;
  const uint2* z64 = (const uint2*)zbuf;
  float bb[8];
  #pragma unroll
  for (int j=0;j<8;++j) bb[j] = b2[8*i + j];
  float pool[8];
  #pragma unroll
  for (int j=0;j<8;++j) pool[j] = 0.f;

  for (int node = qg; node < N_NODES; node += nq){
    int off = offs[node], deg = cnt[node];
    uint2 uz = z64[(unsigned)(node<<4) + i];   // independent, issued early
    float acc[8];
    #pragma unroll
    for (int j=0;j<8;++j) acc[j] = 0.f;
    int e = 0;
    for (; e+2 <= deg; e += 2){
      int s0 = csr[off + e], s1 = csr[off + e + 1];
      uint2 u0 = y64[(unsigned)(s0<<4) + i];
      uint2 u1 = y64[(unsigned)(s1<<4) + i];
      acc[0] += DEC_FP8(u0.x,0) + DEC_FP8(u1.x,0);
      acc[1] += DEC_FP8(u0.x,1) + DEC_FP8(u1.x,1);
      acc[2] += DEC_FP8(u0.x,2) + DEC_FP8(u1.x,2);
      acc[3] += DEC_FP8(u0.x,3) + DEC_FP8(u1.x,3);
      acc[4] += DEC_FP8(u0.y,0) + DEC_FP8(u1.y,0);
      acc[5] += DEC_FP8(u0.y,1) + DEC_FP8(u1.y,1);
      acc[6] += DEC_FP8(u0.y,2) + DEC_FP8(u1.y,2);
      acc[7] += DEC_FP8(u0.y,3) + DEC_FP8(u1.y,3);
    }
    if (e < deg){
      int s0 = csr[off + e];
      uint2 u0 = y64[(unsigned)(s0<<4) + i];
      acc[0] += DEC_FP8(u0.x,0); acc[1] += DEC_FP8(u0.x,1);
      acc[2] += DEC_FP8(u0.x,2); acc[3] += DEC_FP8(u0.x,3);
      acc[4] += DEC_FP8(u0.y,0); acc[5] += DEC_FP8(u0.y,1);
      acc[6] += DEC_FP8(u0.y,2); acc[7] += DEC_FP8(u0.y,3);
    }
    float inv = 1.0f / (float)max(deg,1);
    pool[0] += fmaxf(acc[0]*inv + DEC_FP8(uz.x,0) + bb[0], 0.f);
    pool[1] += fmaxf(acc[1]*inv + DEC_FP8(uz.x,1) + bb[1], 0.f);
    pool[2] += fmaxf(acc[2]*inv + DEC_FP8(uz.x,2) + bb[2], 0.f);
    pool[3] += fmaxf(acc[3]*inv + DEC_FP8(uz.x,3) + bb[3], 0.f);
    pool[4] += fmaxf(acc[4]*inv + DEC_FP8(uz.y,0) + bb[4], 0.f);
    pool[5] += fmaxf(acc[5]*inv + DEC_FP8(uz.y,1) + bb[5], 0.f);
    pool[6] += fmaxf(acc[6]*inv + DEC_FP8(uz.y,2) + bb[6], 0.f);
    pool[7] += fmaxf(acc[7]*inv + DEC_FP8(uz.y,3) + bb[7], 0.f);
  }
  #pragma unroll
  for (int j=0;j<8;++j) atomicAdd(&red[8*i + j], pool[j]);
  __syncthreads();
  if (tid < 128) partials[(size_t)blockIdx.x*128 + tid] = red[tid];
}

// ---- reduce partials -> gsum ----------------------------------------------
__global__ void k_red(const float* __restrict__ partials, float* __restrict__ gsum){
  int t = threadIdx.x;  // 128
  float s = 0.f;
  for (int b = blockIdx.x; b < NB_AGG; b += 64) s += partials[(size_t)b*128 + t];
  atomicAdd(&gsum[t], s);
}

// ---- decoder + softmax + argmax -------------------------------------------
__global__ void k_dec(const float* __restrict__ gsum, const float* __restrict__ Wd,
                      const float* __restrict__ bd, float* __restrict__ out, int out_size){
  int lane = threadIdx.x;  // 64
  float l = -1e30f;
  if (lane < 10){
    float s = bd[lane];
    for (int k=0;k<128;++k) s += (gsum[k]*(1.0f/N_NODES)) * Wd[k*10 + lane];
    l = s;
  }
  float m = l;
  #pragma unroll
  for (int d=1; d<16; d<<=1) m = fmaxf(m, __shfl_xor(m, d));
  float e = (lane<10)? expf(l - m) : 0.f;
  float sum = e;
  #pragma unroll
  for (int d=1; d<16; d<<=1) sum += __shfl_xor(sum, d);
  float p = (lane<10)? e/sum : 0.f;
  if (lane < 10) out[lane] = p;
  float v = p; int idx = (lane<10)? lane : 1000;
  #pragma unroll
  for (int d=1; d<16; d<<=1){
    float ov = __shfl_xor(v, d); int oi = __shfl_xor(idx, d);
    if (ov > v || (ov == v && oi < idx)){ v = ov; idx = oi; }
  }
  if (lane == 0 && out_size > 10) out[10] = (float)idx;
}

// ---- launch ----------------------------------------------------------------
extern "C" void kernel_launch(void* const* d_in, const int* in_sizes, int n_in,
                              void* d_out, int out_size, void* d_ws, size_t ws_size,
                              hipStream_t stream){
  const float* pos = (const float*)d_in[0];
  const int*   face= (const int*)  d_in[1];
  const float* W1l = (const float*)d_in[2];
  const float* W1r = (const float*)d_in[3];
  const float* b1  = (const float*)d_in[4];
  const float* W2l = (const float*)d_in[5];
  const float* W2r = (const float*)d_in[6];
  const float* b2  = (const float*)d_in[7];
  const float* Wd  = (const float*)d_in[8];
  const float* bd  = (const float*)d_in[9];

  char* ws = (char*)d_ws;
  size_t o = 0;
  auto alloc = [&](size_t bytes){ size_t rr = o; o += (bytes + 1023) & ~(size_t)1023; return rr; };
  int*   bfill    = (int*)  (ws + alloc(NBUCKETS*4));            // zeroed
  float* gsum     = (float*)(ws + alloc(512));                   // zeroed
  size_t zero_len = o;
  int*   bbase    = (int*)  (ws + alloc(NBUCKETS*4));
  int*   offs     = (int*)  (ws + alloc((size_t)N_NODES*4));
  int*   cnt      = (int*)  (ws + alloc((size_t)N_NODES*4));
  int*   csr      = (int*)  (ws + alloc((size_t)N_EDGES*4));
  unsigned short* bprep = (unsigned short*)(ws + alloc(131072));
  unsigned short* w1p   = (unsigned short*)(ws + alloc(16384));
  unsigned short* x1bf  = (unsigned short*)(ws + alloc((size_t)N_NODES*8*2));
  unsigned char*  ybuf  = (unsigned char*)(ws + alloc((size_t)N_NODES*128));
  unsigned char*  zbuf  = (unsigned char*)(ws + alloc((size_t)N_NODES*128));
  int2*  pairs    = (int2*) (ws + alloc((size_t)NBUCKETS*CAP_BUCKET*8));
  float* partials = (float*)(ws + alloc((size_t)NB_AGG*128*4));

  hipMemsetAsync(ws, 0, zero_len, stream);

  k_bprep<<<256, 256, 0, stream>>>(W2l, W2r, bprep);
  k_w1prep<<<32, 256, 0, stream>>>(W1l, W1r, w1p);
  k_passA<<<NBUCKETS, 256, 0, stream>>>(face, bfill, pairs);
  k_bscan<<<1, 64, 0, stream>>>(bfill, bbase);
  k_passB<<<NBUCKETS, 512, 0, stream>>>(pairs, bfill, bbase, offs, cnt, csr);
  k_x1<<<(N_NODES+255)/256, 256, 0, stream>>>(pos, csr, offs, cnt, x1bf);
  k_mm<<<MM_BLOCKS, 256, 0, stream>>>(x1bf, w1p, b1, bprep, ybuf, zbuf);
  k_agg2<<<NB_AGG, 256, 0, stream>>>(ybuf, zbuf, csr, offs, cnt, b2, partials);
  k_red<<<64, 128, 0, stream>>>(partials, gsum);
  k_dec<<<1, 64, 0, stream>>>(gsum, Wd, bd, (float*)d_out, out_size);
}